// Round 1
// 260.951 us; speedup vs baseline: 1.0332x; 1.0332x over previous
//
#include <hip/hip_runtime.h>
#include <math.h>
#include <stdint.h>

typedef unsigned short u16;
typedef __bf16 bf16x8 __attribute__((ext_vector_type(8)));
typedef float f32x4 __attribute__((ext_vector_type(4)));

typedef const __attribute__((address_space(1))) void gv_t;
typedef __attribute__((address_space(3))) void lv_t;

__device__ __forceinline__ u16 f2bf(float f) {
    unsigned u = __builtin_bit_cast(unsigned, f);
    return (u16)((u + 0x7FFFu + ((u >> 16) & 1u)) >> 16);
}
__device__ __forceinline__ float bf2f(u16 h) {
    return __builtin_bit_cast(float, (unsigned)h << 16);
}
// async global->LDS, 16B per lane; LDS dest = wave-uniform base + lane*16
__device__ __forceinline__ void gll16(const void* g, void* l) {
    __builtin_amdgcn_global_load_lds((gv_t*)(uintptr_t)g,
                                     (lv_t*)(unsigned)(uintptr_t)l, 16, 0, 0);
}

// ---------------- fp32 -> bf16 elementwise ----------------
__global__ __launch_bounds__(256) void cvt_bf16_kernel(
    const float* __restrict__ in, u16* __restrict__ out, int n4)
{
    int i = blockIdx.x * 256 + threadIdx.x;
    if (i >= n4) return;
    float4 f = ((const float4*)in)[i];
    ushort4 o = make_ushort4(f2bf(f.x), f2bf(f.y), f2bf(f.z), f2bf(f.w));
    ((ushort4*)out)[i] = o;
}

// ---------------- all 4 weights: fp32 [1024][N] -> bf16 [N][1024] ----------------
__global__ __launch_bounds__(256) void cvt_t4_kernel(
    const float* __restrict__ w0, const float* __restrict__ w1,
    const float* __restrict__ w2, const float* __restrict__ w3,
    u16* __restrict__ o0, u16* __restrict__ o1,
    u16* __restrict__ o2, u16* __restrict__ o3)
{
    __shared__ u16 t[64][65];
    const float* in; u16* out; int N;
    switch (blockIdx.z) {
        case 0: in = w0; out = o0; N = 1024; break;
        case 1: in = w1; out = o1; N = 512;  break;
        case 2: in = w2; out = o2; N = 512;  break;
        default: in = w3; out = o3; N = 1024; break;
    }
    int kb = blockIdx.y * 64, nb = blockIdx.x * 64;
    if (nb >= N) return;
    int tid = threadIdx.x;
#pragma unroll
    for (int c = 0; c < 16; ++c) {
        int id = c * 256 + tid;
        int r = id >> 6, n = id & 63;
        t[n][r] = f2bf(in[(size_t)(kb + r) * N + nb + n]);
    }
    __syncthreads();
#pragma unroll
    for (int c = 0; c < 16; ++c) {
        int id = c * 256 + tid;
        int r = id >> 6, n = id & 63;
        out[(size_t)(nb + r) * 1024 + kb + n] = t[r][n];
    }
}

// ---------------- MFMA GEMM, BK=64, XOR-swizzled DMA staging ----------------
// A: [8192][K] bf16, Bt: [N][K] bf16. 128x128 tile, 256 thr = 4 waves 2x2.
// MODE 0: fused QKV, N=2048. cols 0-1023 -> Qo (bias b0, unroped);
//   1024-1535 -> Ko (stride 512, bias b1); 1536-2047 -> V transposed to
//   Vto[((b*8+kvh)*64+d)*1024+s] (bias b2), packed ushort4 along s.
// MODE 1: N=1024, fp32 out Cf = acc + b0 + resid.
template<int MODE>
__global__ __launch_bounds__(256) void gemm_mfma(
    const u16* __restrict__ A, const u16* __restrict__ Bt,
    const float* __restrict__ b0, const float* __restrict__ b1,
    const float* __restrict__ b2,
    const float* __restrict__ resid, float* __restrict__ Cf,
    u16* __restrict__ Qo, u16* __restrict__ Ko, u16* __restrict__ Vto,
    int N, int K)
{
    __shared__ __align__(16) u16 Asl[128 * 64];
    __shared__ __align__(16) u16 Bsl[128 * 64];
    const int tid = threadIdx.x, lane = tid & 63, w = tid >> 6;
    const int quad = lane >> 4, l16 = lane & 15;
    const int bm = blockIdx.y * 128, bn = blockIdx.x * 128;
    const int wm = (w >> 1) * 64, wn = (w & 1) * 64;

    f32x4 acc[4][4] = {};

    const int dr = lane >> 3;                       // row within 8-row band
    const int dcs = (((lane & 7) ^ dr) << 3);       // swizzled global chunk (elems)
    const u16* Ag = &A[(size_t)(bm + w * 32 + dr) * K + dcs];
    const u16* Bg = &Bt[(size_t)(bn + w * 32 + dr) * K + dcs];
    u16* Al = &Asl[(w * 32) * 64];
    u16* Bl = &Bsl[(w * 32) * 64];

    const int sw = l16 & 7;  // fragment-read swizzle

    for (int k0 = 0; k0 < K; k0 += 64) {
#pragma unroll
        for (int c = 0; c < 4; ++c) {
            gll16(Ag + (size_t)(c * 8) * K + k0, Al + c * 8 * 64);
            gll16(Bg + (size_t)(c * 8) * K + k0, Bl + c * 8 * 64);
        }
        __syncthreads();   // drains vmcnt -> staged data visible
        bf16x8 af[4][2], bfr[4][2];
#pragma unroll
        for (int i = 0; i < 4; ++i)
#pragma unroll
            for (int ks = 0; ks < 2; ++ks)
                af[i][ks] = *(const bf16x8*)&Asl[(wm + i * 16 + l16) * 64 + (((ks * 4 + quad) ^ sw) << 3)];
#pragma unroll
        for (int j = 0; j < 4; ++j)
#pragma unroll
            for (int ks = 0; ks < 2; ++ks)
                bfr[j][ks] = *(const bf16x8*)&Bsl[(wn + j * 16 + l16) * 64 + (((ks * 4 + quad) ^ sw) << 3)];
#pragma unroll
        for (int i = 0; i < 4; ++i)
#pragma unroll
            for (int j = 0; j < 4; ++j)
#pragma unroll
                for (int ks = 0; ks < 2; ++ks)
                    acc[i][j] = __builtin_amdgcn_mfma_f32_16x16x32_bf16(af[i][ks], bfr[j][ks], acc[i][j], 0, 0, 0);
        __syncthreads();   // LDS reads done before next stage overwrites
    }

    // epilogue: C/D layout col=lane&15, row=quad*4+reg
#pragma unroll
    for (int j = 0; j < 4; ++j) {
        int col = bn + wn + j * 16 + l16;
        if (MODE == 1) {
            float bb = b0[col];
#pragma unroll
            for (int i = 0; i < 4; ++i) {
                int row0 = bm + wm + i * 16 + quad * 4;
#pragma unroll
                for (int r = 0; r < 4; ++r) {
                    size_t off = (size_t)(row0 + r) * N + col;
                    Cf[off] = acc[i][j][r] + bb + resid[off];
                }
            }
        } else if (col < 1024) {
            float bb = b0[col];
#pragma unroll
            for (int i = 0; i < 4; ++i) {
                int row0 = bm + wm + i * 16 + quad * 4;
#pragma unroll
                for (int r = 0; r < 4; ++r)
                    Qo[(size_t)(row0 + r) * 1024 + col] = f2bf(acc[i][j][r] + bb);
            }
        } else if (col < 1536) {
            int c2 = col - 1024;
            float bb = b1[c2];
#pragma unroll
            for (int i = 0; i < 4; ++i) {
                int row0 = bm + wm + i * 16 + quad * 4;
#pragma unroll
                for (int r = 0; r < 4; ++r)
                    Ko[(size_t)(row0 + r) * 512 + c2] = f2bf(acc[i][j][r] + bb);
            }
        } else {
            int c2 = col - 1536, kvh = c2 >> 6, d = c2 & 63;
            float bb = b2[c2];
#pragma unroll
            for (int i = 0; i < 4; ++i) {
                int row0 = bm + wm + i * 16 + quad * 4;
                int b = row0 >> 10, s = row0 & 1023;
                ushort4 o4;
                o4.x = f2bf(acc[i][j][0] + bb);
                o4.y = f2bf(acc[i][j][1] + bb);
                o4.z = f2bf(acc[i][j][2] + bb);
                o4.w = f2bf(acc[i][j][3] + bb);
                *(ushort4*)&Vto[(size_t)((b * 8 + kvh) * 64 + d) * 1024 + s] = o4;
            }
        }
    }
}

// ---------------- RoPE (interleaved), in place on bf16 (K only) ----------------
__global__ __launch_bounds__(256) void rope_bf16_kernel(
    u16* __restrict__ x, int shift, int stride, int total)
{
    int idx = blockIdx.x * 256 + threadIdx.x;
    if (idx >= total) return;
    int j = idx & 31;
    int h = (idx >> 5) & ((1 << shift) - 1);
    int row = idx >> (5 + shift);
    int pos = row & 1023;
    float inv = exp2f((float)j * -0.4152410118609203f);  // 10000^(-2j/64)
    float sn, cs;
    sincosf((float)pos * inv, &sn, &cs);
    unsigned* p = (unsigned*)&x[(size_t)row * stride + h * 64 + (j << 1)];
    unsigned u = *p;
    float x1 = bf2f((u16)(u & 0xffff)), x2 = bf2f((u16)(u >> 16));
    float y1 = x1 * cs - x2 * sn, y2 = x1 * sn + x2 * cs;
    *p = (unsigned)f2bf(y1) | ((unsigned)f2bf(y2) << 16);
}

// ---------------- MFMA flash attention: 128 q/block, fused Q-RoPE ----------------
// Q: [8192][1024] bf16 (h*64+d, UNroped). K: [8192][512] (kvh*64+d, roped).
// Vt: [(b*8+kvh)*64+d][1024 keys] bf16 (pre-transposed).
// Pipelined: double-buffered Ks/Vts; tile kt+1's global_load_lds issued right
// after the barrier, in flight during tile kt's compute (T3 2-phase recipe).
// One __syncthreads per tile (its vmcnt(0) drain is exactly tile kt's DMA).
// Softmax scale folded into Q-RoPE; l_i computed by ones-MFMA (sums the same
// bf16-truncated P the PV MFMA consumes; accumulates across tiles in C).
// LDS 42.2 KB -> 3 blocks/CU. grid (8 qt, 16 h, 8 b), 256 thr = 4 waves.
__global__ __launch_bounds__(256) void attn_mfma(
    const u16* __restrict__ Q, const u16* __restrict__ K,
    const u16* __restrict__ Vt, u16* __restrict__ O)
{
    __shared__ __align__(16) u16 Ks[2][64 * 64];   // [buf][key][d], swizzled chunks
    __shared__ __align__(16) u16 Vts[2][64 * 64];  // [buf][d][key], swizzled chunks
    __shared__ __align__(16) u16 Ps[128][40];      // [q][key-chunk 32 + pad], wave-private bands

    const int tid = threadIdx.x, lane = tid & 63, w = tid >> 6;
    const int quad = lane >> 4, l16 = lane & 15;
    const int qt = blockIdx.x, h = blockIdx.y, b = blockIdx.z;
    const int kvh = h >> 1;
    const size_t qrow0 = (size_t)b * 1024 + qt * 128;
    const size_t krow0 = (size_t)b * 1024;
    const u16* Vg = Vt + (size_t)((b * 8 + kvh) * 64) * 1024;

    // DMA staging: per wave 16 rows each of K,V^T; 2 calls of 8 rows each.
    const int dr = lane >> 3;                    // row in 8-row band
    const int dcs = (((lane & 7) ^ dr) << 3);    // swizzled global chunk (elems)
    const u16* Kg0 = &K[(krow0 + w * 16 + dr) * 512 + kvh * 64 + dcs];
    const u16* Vg0 = &Vg[(size_t)(w * 16 + dr) * 1024 + dcs];
    const int sw = l16 & 7;
    const float C1 = 0.18033688011112043f;  // 0.125 * log2(e), folded into Q

    // prologue: stage tile 0 into buffer 0 (overlaps Q-RoPE prep below)
#pragma unroll
    for (int c = 0; c < 2; ++c) {
        gll16(Kg0 + (size_t)(c * 8) * 512, &Ks[0][(w * 16 + c * 8) * 64]);
        gll16(Vg0 + (size_t)(c * 8) * 1024, &Vts[0][(w * 16 + c * 8) * 64]);
    }

    // Q fragments with RoPE (and softmax scale C1) applied in-register.
    // B-operand layout: lane holds q, d = ks*32 + quad*8 + (0..7); pairs (2j,2j+1)
    // are in-lane: u32 slot t of the uint4 holds pair j = ks*16 + quad*4 + t.
    bf16x8 qf[2][2];
#pragma unroll
    for (int qg = 0; qg < 2; ++qg) {
        int qrow = w * 32 + qg * 16 + l16;
        float fpos = (float)(qt * 128 + qrow);
#pragma unroll
        for (int ks = 0; ks < 2; ++ks) {
            uint4 qraw = *(const uint4*)&Q[(qrow0 + qrow) * 1024 + h * 64 + ks * 32 + quad * 8];
            unsigned o_[4];
#pragma unroll
            for (int t = 0; t < 4; ++t) {
                int j = ks * 16 + quad * 4 + t;
                float inv = exp2f((float)j * -0.4152410118609203f);
                float sn_, cs_;
                sincosf(fpos * inv, &sn_, &cs_);
                cs_ *= C1; sn_ *= C1;            // fold softmax scale into Q
                unsigned u = (&qraw.x)[t];
                float x1 = bf2f((u16)(u & 0xffff)), x2 = bf2f((u16)(u >> 16));
                float y1 = x1 * cs_ - x2 * sn_, y2 = x1 * sn_ + x2 * cs_;
                o_[t] = (unsigned)f2bf(y1) | ((unsigned)f2bf(y2) << 16);
            }
            qf[qg][ks] = __builtin_bit_cast(bf16x8, make_uint4(o_[0], o_[1], o_[2], o_[3]));
        }
    }

    f32x4 acc_o[2][4] = {};
    f32x4 lsum[2] = {};  // ones-MFMA row-sum accumulator (all regs equal at end)
    const bf16x8 ones = __builtin_bit_cast(bf16x8,
        make_uint4(0x3F803F80u, 0x3F803F80u, 0x3F803F80u, 0x3F803F80u));

    for (int kt = 0; kt < 16; ++kt) {
        const int cur = kt & 1;
        // drains this wave's outstanding DMA (tile kt, in flight during the
        // previous tile's compute) + barrier -> tile kt staged everywhere.
        __syncthreads();

        // prefetch tile kt+1 into the other buffer; its last reader was
        // compute(kt-1), which precedes this barrier for all waves.
        if (kt < 15) {
#pragma unroll
            for (int c = 0; c < 2; ++c) {
                gll16(Kg0 + (size_t)((kt + 1) * 64 + c * 8) * 512,
                      &Ks[cur ^ 1][(w * 16 + c * 8) * 64]);
                gll16(Vg0 + (size_t)(c * 8) * 1024 + (kt + 1) * 64,
                      &Vts[cur ^ 1][(w * 16 + c * 8) * 64]);
            }
        }

        // S^T = K . Q^T : s[qg][nt] holds keys nt*16+quad*4+(0..3) for q-group qg
        f32x4 s[2][4] = {};
#pragma unroll
        for (int ks = 0; ks < 2; ++ks) {
#pragma unroll
            for (int nt = 0; nt < 4; ++nt) {
                bf16x8 ak = *(const bf16x8*)&Ks[cur][(nt * 16 + l16) * 64 + (((ks * 4 + quad) ^ sw) << 3)];
                s[0][nt] = __builtin_amdgcn_mfma_f32_16x16x32_bf16(ak, qf[0][ks], s[0][nt], 0, 0, 0);
                s[1][nt] = __builtin_amdgcn_mfma_f32_16x16x32_bf16(ak, qf[1][ks], s[1][nt], 0, 0, 0);
            }
        }

        // per key-chunk kc (keys kc*32..+31): softmax -> Ps, then PV MFMA.
        // Ps bands are wave-private; same-wave write->read needs no barrier.
#pragma unroll
        for (int kc = 0; kc < 2; ++kc) {
#pragma unroll
            for (int qg = 0; qg < 2; ++qg) {
#pragma unroll
                for (int ntl = 0; ntl < 2; ++ntl) {
                    int nt = kc * 2 + ntl;
                    float p0 = __builtin_amdgcn_exp2f(s[qg][nt][0]);
                    float p1 = __builtin_amdgcn_exp2f(s[qg][nt][1]);
                    unsigned pk0 = __builtin_amdgcn_perm(
                        __builtin_bit_cast(unsigned, p1),
                        __builtin_bit_cast(unsigned, p0), 0x07060302u);
                    float p2 = __builtin_amdgcn_exp2f(s[qg][nt][2]);
                    float p3 = __builtin_amdgcn_exp2f(s[qg][nt][3]);
                    unsigned pk1 = __builtin_amdgcn_perm(
                        __builtin_bit_cast(unsigned, p3),
                        __builtin_bit_cast(unsigned, p2), 0x07060302u);
                    *(uint2*)&Ps[w * 32 + qg * 16 + l16][ntl * 16 + quad * 4] = make_uint2(pk0, pk1);
                }
            }
            bf16x8 bp0 = *(const bf16x8*)&Ps[w * 32 + l16][quad * 8];
            bf16x8 bp1 = *(const bf16x8*)&Ps[w * 32 + 16 + l16][quad * 8];
            // l_i = P . 1 via ones-MFMA (sums the exact bf16 P used by PV)
            lsum[0] = __builtin_amdgcn_mfma_f32_16x16x32_bf16(ones, bp0, lsum[0], 0, 0, 0);
            lsum[1] = __builtin_amdgcn_mfma_f32_16x16x32_bf16(ones, bp1, lsum[1], 0, 0, 0);
            // O^T += V^T(chunk kc) . P^T(chunk kc)
#pragma unroll
            for (int nt = 0; nt < 4; ++nt) {
                bf16x8 av = *(const bf16x8*)&Vts[cur][(nt * 16 + l16) * 64 + (((kc * 4 + quad) ^ sw) << 3)];
                acc_o[0][nt] = __builtin_amdgcn_mfma_f32_16x16x32_bf16(av, bp0, acc_o[0][nt], 0, 0, 0);
                acc_o[1][nt] = __builtin_amdgcn_mfma_f32_16x16x32_bf16(av, bp1, acc_o[1][nt], 0, 0, 0);
            }
        }
        // no trailing barrier: next iteration's __syncthreads covers the
        // read-before-overwrite hazard (prefetch targets the other buffer).
    }

    // epilogue: lsum already holds full row sums (all lanes/regs for q=l16)
#pragma unroll
    for (int qg = 0; qg < 2; ++qg) {
        float rl = 1.0f / lsum[qg][0];
        size_t orow = (qrow0 + w * 32 + qg * 16 + l16) * 1024 + h * 64;
#pragma unroll
        for (int nt = 0; nt < 4; ++nt) {
            ushort4 o4;
            o4.x = f2bf(acc_o[qg][nt][0] * rl);
            o4.y = f2bf(acc_o[qg][nt][1] * rl);
            o4.z = f2bf(acc_o[qg][nt][2] * rl);
            o4.w = f2bf(acc_o[qg][nt][3] * rl);
            *(ushort4*)&O[orow + nt * 16 + quad * 4] = o4;
        }
    }
}

// ---------------- LayerNorm in place on [8192][1024] fp32 ----------------
__global__ __launch_bounds__(256) void ln_kernel(float* __restrict__ io,
    const float* __restrict__ gamma, const float* __restrict__ beta)
{
    int row = blockIdx.x;
    int tid = threadIdx.x;
    float* p = io + (size_t)row * 1024;
    float4 x = *reinterpret_cast<const float4*>(&p[tid << 2]);
    float s = x.x + x.y + x.z + x.w;
    float ss = fmaf(x.x, x.x, fmaf(x.y, x.y, fmaf(x.z, x.z, x.w * x.w)));
#pragma unroll
    for (int off = 32; off > 0; off >>= 1) {
        s  += __shfl_down(s, off);
        ss += __shfl_down(ss, off);
    }
    __shared__ float rs[4], rss[4];
    int lane = tid & 63, wid = tid >> 6;
    if (lane == 0) { rs[wid] = s; rss[wid] = ss; }
    __syncthreads();
    float S = rs[0] + rs[1] + rs[2] + rs[3];
    float SS = rss[0] + rss[1] + rss[2] + rss[3];
    float mu = S * (1.0f / 1024.0f);
    float var = SS * (1.0f / 1024.0f) - mu * mu;
    float rstd = rsqrtf(var + 1e-12f);
    float4 g = *reinterpret_cast<const float4*>(&gamma[tid << 2]);
    float4 be = *reinterpret_cast<const float4*>(&beta[tid << 2]);
    float4 o;
    o.x = (x.x - mu) * rstd * g.x + be.x;
    o.y = (x.y - mu) * rstd * g.y + be.y;
    o.z = (x.z - mu) * rstd * g.z + be.z;
    o.w = (x.w - mu) * rstd * g.w + be.w;
    *reinterpret_cast<float4*>(&p[tid << 2]) = o;
}

// ---------------- launch ----------------
extern "C" void kernel_launch(void* const* d_in, const int* in_sizes, int n_in,
                              void* d_out, int out_size, void* d_ws, size_t ws_size,
                              hipStream_t stream)
{
    (void)in_sizes; (void)n_in; (void)out_size; (void)ws_size;
    const float* hidden = (const float*)d_in[0];
    const float* Wq = (const float*)d_in[1];
    const float* bq = (const float*)d_in[2];
    const float* Wk = (const float*)d_in[3];
    const float* bk = (const float*)d_in[4];
    const float* Wv = (const float*)d_in[5];
    const float* bv = (const float*)d_in[6];
    const float* Wo = (const float*)d_in[7];
    const float* bo = (const float*)d_in[8];
    const float* g  = (const float*)d_in[9];
    const float* be = (const float*)d_in[10];
    float* out = (float*)d_out;

    // workspace layout (Wqt/Wkt/Wvt contiguous => one [2048][1024] B^T matrix)
    u16* hb  = (u16*)d_ws;                       // [8192][1024] bf16 hidden
    u16* Wqt = hb  + (size_t)8192 * 1024;        // [1024][1024] Wq^T
    u16* Wkt = Wqt + (size_t)1024 * 1024;        // [512][1024]  Wk^T
    u16* Wvt = Wkt + (size_t)512 * 1024;         // [512][1024]  Wv^T
    u16* Wot = Wvt + (size_t)512 * 1024;         // [1024][1024] Wo^T
    u16* Qb  = Wot + (size_t)1024 * 1024;        // [8192][1024] Q (then attn out)
    u16* Kb  = Qb  + (size_t)8192 * 1024;        // [8192][512]  K
    u16* Vtb = Kb  + (size_t)8192 * 512;         // [4096][1024] V^T per (b,kvh)
    // total ~66 MB

    cvt_bf16_kernel<<<8192, 256, 0, stream>>>(hidden, hb, 8192 * 1024 / 4);
    cvt_t4_kernel<<<dim3(16, 16, 4), 256, 0, stream>>>(Wq, Wk, Wv, Wo, Wqt, Wkt, Wvt, Wot);

    // fused QKV: N=2048 (Bt = [Wq^T;Wk^T;Wv^T]), writes Qb (unroped), Kb, Vtb (V transposed)
    gemm_mfma<0><<<dim3(16, 64), 256, 0, stream>>>(hb, Wqt, bq, bk, bv,
        nullptr, nullptr, Qb, Kb, Vtb, 2048, 1024);

    // RoPE on K only (Q roped inside attn)
    rope_bf16_kernel<<<8192, 256, 0, stream>>>(Kb, 3, 512, 8192 * 8 * 32);

    attn_mfma<<<dim3(8, 16, 8), 256, 0, stream>>>(Qb, Kb, Vtb, Qb);

    // out-proj: fp32 out + bias + resid
    gemm_mfma<1><<<dim3(8, 64), 256, 0, stream>>>(Qb, Wot, bo, nullptr, nullptr,
        hidden, out, nullptr, nullptr, nullptr, 1024, 1024);
    ln_kernel<<<8192, 256, 0, stream>>>(out, g, be);
}

// Round 2
// 249.920 us; speedup vs baseline: 1.0788x; 1.0441x over previous
//
#include <hip/hip_runtime.h>
#include <math.h>
#include <stdint.h>

typedef unsigned short u16;
typedef __bf16 bf16x8 __attribute__((ext_vector_type(8)));
typedef float f32x4 __attribute__((ext_vector_type(4)));

typedef const __attribute__((address_space(1))) void gv_t;
typedef __attribute__((address_space(3))) void lv_t;

__device__ __forceinline__ u16 f2bf(float f) {
    unsigned u = __builtin_bit_cast(unsigned, f);
    return (u16)((u + 0x7FFFu + ((u >> 16) & 1u)) >> 16);
}
__device__ __forceinline__ float bf2f(u16 h) {
    return __builtin_bit_cast(float, (unsigned)h << 16);
}
// async global->LDS, 16B per lane; LDS dest = wave-uniform base + lane*16
__device__ __forceinline__ void gll16(const void* g, void* l) {
    __builtin_amdgcn_global_load_lds((gv_t*)(uintptr_t)g,
                                     (lv_t*)(unsigned)(uintptr_t)l, 16, 0, 0);
}

// ---------------- fp32 -> bf16 elementwise ----------------
__global__ __launch_bounds__(256) void cvt_bf16_kernel(
    const float* __restrict__ in, u16* __restrict__ out, int n4)
{
    int i = blockIdx.x * 256 + threadIdx.x;
    if (i >= n4) return;
    float4 f = ((const float4*)in)[i];
    ushort4 o = make_ushort4(f2bf(f.x), f2bf(f.y), f2bf(f.z), f2bf(f.w));
    ((ushort4*)out)[i] = o;
}

// ---------------- all 4 weights: fp32 [1024][N] -> bf16 [N][1024] ----------------
__global__ __launch_bounds__(256) void cvt_t4_kernel(
    const float* __restrict__ w0, const float* __restrict__ w1,
    const float* __restrict__ w2, const float* __restrict__ w3,
    u16* __restrict__ o0, u16* __restrict__ o1,
    u16* __restrict__ o2, u16* __restrict__ o3)
{
    __shared__ u16 t[64][65];
    const float* in; u16* out; int N;
    switch (blockIdx.z) {
        case 0: in = w0; out = o0; N = 1024; break;
        case 1: in = w1; out = o1; N = 512;  break;
        case 2: in = w2; out = o2; N = 512;  break;
        default: in = w3; out = o3; N = 1024; break;
    }
    int kb = blockIdx.y * 64, nb = blockIdx.x * 64;
    if (nb >= N) return;
    int tid = threadIdx.x;
#pragma unroll
    for (int c = 0; c < 16; ++c) {
        int id = c * 256 + tid;
        int r = id >> 6, n = id & 63;
        t[n][r] = f2bf(in[(size_t)(kb + r) * N + nb + n]);
    }
    __syncthreads();
#pragma unroll
    for (int c = 0; c < 16; ++c) {
        int id = c * 256 + tid;
        int r = id >> 6, n = id & 63;
        out[(size_t)(nb + r) * 1024 + kb + n] = t[r][n];
    }
}

// ---------------- MFMA GEMM, BK=64, XOR-swizzled DMA staging ----------------
// A: [8192][K] bf16, Bt: [N][K] bf16. 128x128 tile, 256 thr = 4 waves 2x2.
// MODE 0: fused QKV, N=2048. cols 0-1023 -> Qo (bias b0, unroped);
//   1024-1535 -> Ko (stride 512, bias b1); 1536-2047 -> V transposed to
//   Vto[((b*8+kvh)*64+d)*1024+s] (bias b2), packed ushort4 along s.
// MODE 1: N=1024, fp32 out Cf = acc + b0 + resid.
template<int MODE>
__global__ __launch_bounds__(256) void gemm_mfma(
    const u16* __restrict__ A, const u16* __restrict__ Bt,
    const float* __restrict__ b0, const float* __restrict__ b1,
    const float* __restrict__ b2,
    const float* __restrict__ resid, float* __restrict__ Cf,
    u16* __restrict__ Qo, u16* __restrict__ Ko, u16* __restrict__ Vto,
    int N, int K)
{
    __shared__ __align__(16) u16 Asl[128 * 64];
    __shared__ __align__(16) u16 Bsl[128 * 64];
    const int tid = threadIdx.x, lane = tid & 63, w = tid >> 6;
    const int quad = lane >> 4, l16 = lane & 15;
    const int bm = blockIdx.y * 128, bn = blockIdx.x * 128;
    const int wm = (w >> 1) * 64, wn = (w & 1) * 64;

    f32x4 acc[4][4] = {};

    const int dr = lane >> 3;                       // row within 8-row band
    const int dcs = (((lane & 7) ^ dr) << 3);       // swizzled global chunk (elems)
    const u16* Ag = &A[(size_t)(bm + w * 32 + dr) * K + dcs];
    const u16* Bg = &Bt[(size_t)(bn + w * 32 + dr) * K + dcs];
    u16* Al = &Asl[(w * 32) * 64];
    u16* Bl = &Bsl[(w * 32) * 64];

    const int sw = l16 & 7;  // fragment-read swizzle

    for (int k0 = 0; k0 < K; k0 += 64) {
#pragma unroll
        for (int c = 0; c < 4; ++c) {
            gll16(Ag + (size_t)(c * 8) * K + k0, Al + c * 8 * 64);
            gll16(Bg + (size_t)(c * 8) * K + k0, Bl + c * 8 * 64);
        }
        __syncthreads();   // drains vmcnt -> staged data visible
        bf16x8 af[4][2], bfr[4][2];
#pragma unroll
        for (int i = 0; i < 4; ++i)
#pragma unroll
            for (int ks = 0; ks < 2; ++ks)
                af[i][ks] = *(const bf16x8*)&Asl[(wm + i * 16 + l16) * 64 + (((ks * 4 + quad) ^ sw) << 3)];
#pragma unroll
        for (int j = 0; j < 4; ++j)
#pragma unroll
            for (int ks = 0; ks < 2; ++ks)
                bfr[j][ks] = *(const bf16x8*)&Bsl[(wn + j * 16 + l16) * 64 + (((ks * 4 + quad) ^ sw) << 3)];
#pragma unroll
        for (int i = 0; i < 4; ++i)
#pragma unroll
            for (int j = 0; j < 4; ++j)
#pragma unroll
                for (int ks = 0; ks < 2; ++ks)
                    acc[i][j] = __builtin_amdgcn_mfma_f32_16x16x32_bf16(af[i][ks], bfr[j][ks], acc[i][j], 0, 0, 0);
        __syncthreads();   // LDS reads done before next stage overwrites
    }

    // epilogue: C/D layout col=lane&15, row=quad*4+reg
#pragma unroll
    for (int j = 0; j < 4; ++j) {
        int col = bn + wn + j * 16 + l16;
        if (MODE == 1) {
            float bb = b0[col];
#pragma unroll
            for (int i = 0; i < 4; ++i) {
                int row0 = bm + wm + i * 16 + quad * 4;
#pragma unroll
                for (int r = 0; r < 4; ++r) {
                    size_t off = (size_t)(row0 + r) * N + col;
                    Cf[off] = acc[i][j][r] + bb + resid[off];
                }
            }
        } else if (col < 1024) {
            float bb = b0[col];
#pragma unroll
            for (int i = 0; i < 4; ++i) {
                int row0 = bm + wm + i * 16 + quad * 4;
#pragma unroll
                for (int r = 0; r < 4; ++r)
                    Qo[(size_t)(row0 + r) * 1024 + col] = f2bf(acc[i][j][r] + bb);
            }
        } else if (col < 1536) {
            int c2 = col - 1024;
            float bb = b1[c2];
#pragma unroll
            for (int i = 0; i < 4; ++i) {
                int row0 = bm + wm + i * 16 + quad * 4;
#pragma unroll
                for (int r = 0; r < 4; ++r)
                    Ko[(size_t)(row0 + r) * 512 + c2] = f2bf(acc[i][j][r] + bb);
            }
        } else {
            int c2 = col - 1536, kvh = c2 >> 6, d = c2 & 63;
            float bb = b2[c2];
#pragma unroll
            for (int i = 0; i < 4; ++i) {
                int row0 = bm + wm + i * 16 + quad * 4;
                int b = row0 >> 10, s = row0 & 1023;
                ushort4 o4;
                o4.x = f2bf(acc[i][j][0] + bb);
                o4.y = f2bf(acc[i][j][1] + bb);
                o4.z = f2bf(acc[i][j][2] + bb);
                o4.w = f2bf(acc[i][j][3] + bb);
                *(ushort4*)&Vto[(size_t)((b * 8 + kvh) * 64 + d) * 1024 + s] = o4;
            }
        }
    }
}

// ---------------- RoPE (interleaved), in place on bf16 (K only) ----------------
__global__ __launch_bounds__(256) void rope_bf16_kernel(
    u16* __restrict__ x, int shift, int stride, int total)
{
    int idx = blockIdx.x * 256 + threadIdx.x;
    if (idx >= total) return;
    int j = idx & 31;
    int h = (idx >> 5) & ((1 << shift) - 1);
    int row = idx >> (5 + shift);
    int pos = row & 1023;
    float inv = exp2f((float)j * -0.4152410118609203f);  // 10000^(-2j/64)
    float sn, cs;
    sincosf((float)pos * inv, &sn, &cs);
    unsigned* p = (unsigned*)&x[(size_t)row * stride + h * 64 + (j << 1)];
    unsigned u = *p;
    float x1 = bf2f((u16)(u & 0xffff)), x2 = bf2f((u16)(u >> 16));
    float y1 = x1 * cs - x2 * sn, y2 = x1 * sn + x2 * cs;
    *p = (unsigned)f2bf(y1) | ((unsigned)f2bf(y2) << 16);
}

// ---------------- MFMA flash attention: 128 q/block, fused Q-RoPE ----------------
// Q: [8192][1024] bf16 (h*64+d, UNroped). K: [8192][512] (kvh*64+d, roped).
// Vt: [(b*8+kvh)*64+d][1024 keys] bf16 (pre-transposed).
// Pipelined: double-buffered Ks/Vts (T3 2-phase); one __syncthreads per tile
// (its vmcnt(0) drain is exactly tile kt's DMA, in flight during kt-1 compute).
// Ps shrunk to [64][40]: PV is q-group-serial with V fragments cached in regs,
// so each wave time-shares a 16-row Ps band (in-wave LDS ordering, no barrier).
// LDS 37.9 KB -> 4 blocks/CU; grid 1024 = 256 CU x 4 -> fully co-resident.
// XCD-chunked swizzle: hardware id%8 = XCD; nid = (id&7)*128 + (id>>3) puts
// each batch b (K+V 2.1 MB, fits 4 MB L2) on exactly one XCD.
// T5 setprio wrapped around MFMA clusters (phase-diverse waves, m191 +4-7%).
__global__ __launch_bounds__(256, 4) void attn_mfma(
    const u16* __restrict__ Q, const u16* __restrict__ K,
    const u16* __restrict__ Vt, u16* __restrict__ O)
{
    __shared__ __align__(16) u16 Ks[2][64 * 64];   // [buf][key][d], swizzled chunks
    __shared__ __align__(16) u16 Vts[2][64 * 64];  // [buf][d][key], swizzled chunks
    __shared__ __align__(16) u16 Ps[64][40];       // [wave 16-row band][32 keys + pad]

    const int tid = threadIdx.x, lane = tid & 63, w = tid >> 6;
    const int quad = lane >> 4, l16 = lane & 15;
    const int id = blockIdx.x;
    const int nid = (id & 7) * 128 + (id >> 3);    // XCD-chunked (id%8 -> XCD)
    const int qt = nid & 7, h = (nid >> 3) & 15, b = nid >> 7;
    const int kvh = h >> 1;
    const size_t qrow0 = (size_t)b * 1024 + qt * 128;
    const size_t krow0 = (size_t)b * 1024;
    const u16* Vg = Vt + (size_t)((b * 8 + kvh) * 64) * 1024;

    // DMA staging: per wave 16 rows each of K,V^T; 2 calls of 8 rows each.
    const int dr = lane >> 3;                    // row in 8-row band
    const int dcs = (((lane & 7) ^ dr) << 3);    // swizzled global chunk (elems)
    const u16* Kg0 = &K[(krow0 + w * 16 + dr) * 512 + kvh * 64 + dcs];
    const u16* Vg0 = &Vg[(size_t)(w * 16 + dr) * 1024 + dcs];
    const int sw = l16 & 7;
    const float C1 = 0.18033688011112043f;  // 0.125 * log2(e), folded into Q

    // prologue: stage tile 0 into buffer 0 (overlaps Q-RoPE prep below)
#pragma unroll
    for (int c = 0; c < 2; ++c) {
        gll16(Kg0 + (size_t)(c * 8) * 512, &Ks[0][(w * 16 + c * 8) * 64]);
        gll16(Vg0 + (size_t)(c * 8) * 1024, &Vts[0][(w * 16 + c * 8) * 64]);
    }

    // Q fragments with RoPE (and softmax scale C1) applied in-register.
    // B-operand layout: lane holds q, d = ks*32 + quad*8 + (0..7); pairs (2j,2j+1)
    // are in-lane: u32 slot t of the uint4 holds pair j = ks*16 + quad*4 + t.
    bf16x8 qf[2][2];
#pragma unroll
    for (int qg = 0; qg < 2; ++qg) {
        int qrow = w * 32 + qg * 16 + l16;
        float fpos = (float)(qt * 128 + qrow);
#pragma unroll
        for (int ks = 0; ks < 2; ++ks) {
            uint4 qraw = *(const uint4*)&Q[(qrow0 + qrow) * 1024 + h * 64 + ks * 32 + quad * 8];
            unsigned o_[4];
#pragma unroll
            for (int t = 0; t < 4; ++t) {
                int j = ks * 16 + quad * 4 + t;
                float inv = exp2f((float)j * -0.4152410118609203f);
                float sn_, cs_;
                sincosf(fpos * inv, &sn_, &cs_);
                cs_ *= C1; sn_ *= C1;            // fold softmax scale into Q
                unsigned u = (&qraw.x)[t];
                float x1 = bf2f((u16)(u & 0xffff)), x2 = bf2f((u16)(u >> 16));
                float y1 = x1 * cs_ - x2 * sn_, y2 = x1 * sn_ + x2 * cs_;
                o_[t] = (unsigned)f2bf(y1) | ((unsigned)f2bf(y2) << 16);
            }
            qf[qg][ks] = __builtin_bit_cast(bf16x8, make_uint4(o_[0], o_[1], o_[2], o_[3]));
        }
    }

    f32x4 acc_o[2][4] = {};
    f32x4 lsum[2] = {};  // ones-MFMA row-sum accumulator (all regs equal at end)
    const bf16x8 ones = __builtin_bit_cast(bf16x8,
        make_uint4(0x3F803F80u, 0x3F803F80u, 0x3F803F80u, 0x3F803F80u));

    for (int kt = 0; kt < 16; ++kt) {
        const int cur = kt & 1;
        // drains this wave's outstanding DMA (tile kt, in flight during the
        // previous tile's compute) + barrier -> tile kt staged everywhere.
        __syncthreads();

        // prefetch tile kt+1 into the other buffer; its last reader was
        // compute(kt-1), which precedes this barrier for all waves.
        if (kt < 15) {
#pragma unroll
            for (int c = 0; c < 2; ++c) {
                gll16(Kg0 + (size_t)((kt + 1) * 64 + c * 8) * 512,
                      &Ks[cur ^ 1][(w * 16 + c * 8) * 64]);
                gll16(Vg0 + (size_t)(c * 8) * 1024 + (kt + 1) * 64,
                      &Vts[cur ^ 1][(w * 16 + c * 8) * 64]);
            }
        }

        // S^T = K . Q^T : s[qg][nt] holds keys nt*16+quad*4+(0..3) for q-group qg
        f32x4 s[2][4] = {};
        __builtin_amdgcn_s_setprio(1);
#pragma unroll
        for (int ks = 0; ks < 2; ++ks) {
#pragma unroll
            for (int nt = 0; nt < 4; ++nt) {
                bf16x8 ak = *(const bf16x8*)&Ks[cur][(nt * 16 + l16) * 64 + (((ks * 4 + quad) ^ sw) << 3)];
                s[0][nt] = __builtin_amdgcn_mfma_f32_16x16x32_bf16(ak, qf[0][ks], s[0][nt], 0, 0, 0);
                s[1][nt] = __builtin_amdgcn_mfma_f32_16x16x32_bf16(ak, qf[1][ks], s[1][nt], 0, 0, 0);
            }
        }
        __builtin_amdgcn_s_setprio(0);

        // per key-chunk kc (keys kc*32..+31): softmax -> Ps band, then PV MFMA.
        // Ps band is wave-private AND time-shared across (kc, qg): in-wave LDS
        // ordering guarantees qg0's read completes before qg1's overwrite.
#pragma unroll
        for (int kc = 0; kc < 2; ++kc) {
            bf16x8 av[4];  // V fragments cached: shared by both q-groups
#pragma unroll
            for (int nt = 0; nt < 4; ++nt)
                av[nt] = *(const bf16x8*)&Vts[cur][(nt * 16 + l16) * 64 + (((kc * 4 + quad) ^ sw) << 3)];
#pragma unroll
            for (int qg = 0; qg < 2; ++qg) {
#pragma unroll
                for (int ntl = 0; ntl < 2; ++ntl) {
                    int nt = kc * 2 + ntl;
                    float p0 = __builtin_amdgcn_exp2f(s[qg][nt][0]);
                    float p1 = __builtin_amdgcn_exp2f(s[qg][nt][1]);
                    unsigned pk0 = __builtin_amdgcn_perm(
                        __builtin_bit_cast(unsigned, p1),
                        __builtin_bit_cast(unsigned, p0), 0x07060302u);
                    float p2 = __builtin_amdgcn_exp2f(s[qg][nt][2]);
                    float p3 = __builtin_amdgcn_exp2f(s[qg][nt][3]);
                    unsigned pk1 = __builtin_amdgcn_perm(
                        __builtin_bit_cast(unsigned, p3),
                        __builtin_bit_cast(unsigned, p2), 0x07060302u);
                    *(uint2*)&Ps[w * 16 + l16][ntl * 16 + quad * 4] = make_uint2(pk0, pk1);
                }
                bf16x8 bp = *(const bf16x8*)&Ps[w * 16 + l16][quad * 8];
                __builtin_amdgcn_s_setprio(1);
                // l_i = P . 1 via ones-MFMA (sums the exact bf16 P used by PV)
                lsum[qg] = __builtin_amdgcn_mfma_f32_16x16x32_bf16(ones, bp, lsum[qg], 0, 0, 0);
                // O^T += V^T(chunk kc) . P^T(chunk kc)
#pragma unroll
                for (int nt = 0; nt < 4; ++nt)
                    acc_o[qg][nt] = __builtin_amdgcn_mfma_f32_16x16x32_bf16(av[nt], bp, acc_o[qg][nt], 0, 0, 0);
                __builtin_amdgcn_s_setprio(0);
            }
        }
        // no trailing barrier: next iteration's __syncthreads covers the
        // read-before-overwrite hazard (prefetch targets the other buffer).
    }

    // epilogue: lsum already holds full row sums (all lanes/regs for q=l16)
#pragma unroll
    for (int qg = 0; qg < 2; ++qg) {
        float rl = 1.0f / lsum[qg][0];
        size_t orow = (qrow0 + w * 32 + qg * 16 + l16) * 1024 + h * 64;
#pragma unroll
        for (int nt = 0; nt < 4; ++nt) {
            ushort4 o4;
            o4.x = f2bf(acc_o[qg][nt][0] * rl);
            o4.y = f2bf(acc_o[qg][nt][1] * rl);
            o4.z = f2bf(acc_o[qg][nt][2] * rl);
            o4.w = f2bf(acc_o[qg][nt][3] * rl);
            *(ushort4*)&O[orow + nt * 16 + quad * 4] = o4;
        }
    }
}

// ---------------- LayerNorm in place on [8192][1024] fp32 ----------------
__global__ __launch_bounds__(256) void ln_kernel(float* __restrict__ io,
    const float* __restrict__ gamma, const float* __restrict__ beta)
{
    int row = blockIdx.x;
    int tid = threadIdx.x;
    float* p = io + (size_t)row * 1024;
    float4 x = *reinterpret_cast<const float4*>(&p[tid << 2]);
    float s = x.x + x.y + x.z + x.w;
    float ss = fmaf(x.x, x.x, fmaf(x.y, x.y, fmaf(x.z, x.z, x.w * x.w)));
#pragma unroll
    for (int off = 32; off > 0; off >>= 1) {
        s  += __shfl_down(s, off);
        ss += __shfl_down(ss, off);
    }
    __shared__ float rs[4], rss[4];
    int lane = tid & 63, wid = tid >> 6;
    if (lane == 0) { rs[wid] = s; rss[wid] = ss; }
    __syncthreads();
    float S = rs[0] + rs[1] + rs[2] + rs[3];
    float SS = rss[0] + rss[1] + rss[2] + rss[3];
    float mu = S * (1.0f / 1024.0f);
    float var = SS * (1.0f / 1024.0f) - mu * mu;
    float rstd = rsqrtf(var + 1e-12f);
    float4 g = *reinterpret_cast<const float4*>(&gamma[tid << 2]);
    float4 be = *reinterpret_cast<const float4*>(&beta[tid << 2]);
    float4 o;
    o.x = (x.x - mu) * rstd * g.x + be.x;
    o.y = (x.y - mu) * rstd * g.y + be.y;
    o.z = (x.z - mu) * rstd * g.z + be.z;
    o.w = (x.w - mu) * rstd * g.w + be.w;
    *reinterpret_cast<float4*>(&p[tid << 2]) = o;
}

// ---------------- launch ----------------
extern "C" void kernel_launch(void* const* d_in, const int* in_sizes, int n_in,
                              void* d_out, int out_size, void* d_ws, size_t ws_size,
                              hipStream_t stream)
{
    (void)in_sizes; (void)n_in; (void)out_size; (void)ws_size;
    const float* hidden = (const float*)d_in[0];
    const float* Wq = (const float*)d_in[1];
    const float* bq = (const float*)d_in[2];
    const float* Wk = (const float*)d_in[3];
    const float* bk = (const float*)d_in[4];
    const float* Wv = (const float*)d_in[5];
    const float* bv = (const float*)d_in[6];
    const float* Wo = (const float*)d_in[7];
    const float* bo = (const float*)d_in[8];
    const float* g  = (const float*)d_in[9];
    const float* be = (const float*)d_in[10];
    float* out = (float*)d_out;

    // workspace layout (Wqt/Wkt/Wvt contiguous => one [2048][1024] B^T matrix)
    u16* hb  = (u16*)d_ws;                       // [8192][1024] bf16 hidden
    u16* Wqt = hb  + (size_t)8192 * 1024;        // [1024][1024] Wq^T
    u16* Wkt = Wqt + (size_t)1024 * 1024;        // [512][1024]  Wk^T
    u16* Wvt = Wkt + (size_t)512 * 1024;         // [512][1024]  Wv^T
    u16* Wot = Wvt + (size_t)512 * 1024;         // [1024][1024] Wo^T
    u16* Qb  = Wot + (size_t)1024 * 1024;        // [8192][1024] Q (then attn out)
    u16* Kb  = Qb  + (size_t)8192 * 1024;        // [8192][512]  K
    u16* Vtb = Kb  + (size_t)8192 * 512;         // [4096][1024] V^T per (b,kvh)
    // total ~66 MB

    cvt_bf16_kernel<<<8192, 256, 0, stream>>>(hidden, hb, 8192 * 1024 / 4);
    cvt_t4_kernel<<<dim3(16, 16, 4), 256, 0, stream>>>(Wq, Wk, Wv, Wo, Wqt, Wkt, Wvt, Wot);

    // fused QKV: N=2048 (Bt = [Wq^T;Wk^T;Wv^T]), writes Qb (unroped), Kb, Vtb (V transposed)
    gemm_mfma<0><<<dim3(16, 64), 256, 0, stream>>>(hb, Wqt, bq, bk, bv,
        nullptr, nullptr, Qb, Kb, Vtb, 2048, 1024);

    // RoPE on K only (Q roped inside attn)
    rope_bf16_kernel<<<8192, 256, 0, stream>>>(Kb, 3, 512, 8192 * 8 * 32);

    attn_mfma<<<dim3(1024), 256, 0, stream>>>(Qb, Kb, Vtb, Qb);

    // out-proj: fp32 out + bias + resid
    gemm_mfma<1><<<dim3(8, 64), 256, 0, stream>>>(Qb, Wot, bo, nullptr, nullptr,
        hidden, out, nullptr, nullptr, nullptr, 1024, 1024);
    ln_kernel<<<8192, 256, 0, stream>>>(out, g, be);
}

// Round 3
// 244.709 us; speedup vs baseline: 1.1017x; 1.0213x over previous
//
#include <hip/hip_runtime.h>
#include <math.h>
#include <stdint.h>

typedef unsigned short u16;
typedef __bf16 bf16x8 __attribute__((ext_vector_type(8)));
typedef float f32x4 __attribute__((ext_vector_type(4)));

typedef const __attribute__((address_space(1))) void gv_t;
typedef __attribute__((address_space(3))) void lv_t;

__device__ __forceinline__ u16 f2bf(float f) {
    unsigned u = __builtin_bit_cast(unsigned, f);
    return (u16)((u + 0x7FFFu + ((u >> 16) & 1u)) >> 16);
}
__device__ __forceinline__ float bf2f(u16 h) {
    return __builtin_bit_cast(float, (unsigned)h << 16);
}
// async global->LDS, 16B per lane; LDS dest = wave-uniform base + lane*16
__device__ __forceinline__ void gll16(const void* g, void* l) {
    __builtin_amdgcn_global_load_lds((gv_t*)(uintptr_t)g,
                                     (lv_t*)(unsigned)(uintptr_t)l, 16, 0, 0);
}

// ---------------- fp32 -> bf16 elementwise ----------------
__global__ __launch_bounds__(256) void cvt_bf16_kernel(
    const float* __restrict__ in, u16* __restrict__ out, int n4)
{
    int i = blockIdx.x * 256 + threadIdx.x;
    if (i >= n4) return;
    float4 f = ((const float4*)in)[i];
    ushort4 o = make_ushort4(f2bf(f.x), f2bf(f.y), f2bf(f.z), f2bf(f.w));
    ((ushort4*)out)[i] = o;
}

// ---------------- all 4 weights: fp32 [1024][N] -> bf16 [N][1024] ----------------
__global__ __launch_bounds__(256) void cvt_t4_kernel(
    const float* __restrict__ w0, const float* __restrict__ w1,
    const float* __restrict__ w2, const float* __restrict__ w3,
    u16* __restrict__ o0, u16* __restrict__ o1,
    u16* __restrict__ o2, u16* __restrict__ o3)
{
    __shared__ u16 t[64][65];
    const float* in; u16* out; int N;
    switch (blockIdx.z) {
        case 0: in = w0; out = o0; N = 1024; break;
        case 1: in = w1; out = o1; N = 512;  break;
        case 2: in = w2; out = o2; N = 512;  break;
        default: in = w3; out = o3; N = 1024; break;
    }
    int kb = blockIdx.y * 64, nb = blockIdx.x * 64;
    if (nb >= N) return;
    int tid = threadIdx.x;
#pragma unroll
    for (int c = 0; c < 16; ++c) {
        int id = c * 256 + tid;
        int r = id >> 6, n = id & 63;
        t[n][r] = f2bf(in[(size_t)(kb + r) * N + nb + n]);
    }
    __syncthreads();
#pragma unroll
    for (int c = 0; c < 16; ++c) {
        int id = c * 256 + tid;
        int r = id >> 6, n = id & 63;
        out[(size_t)(nb + r) * 1024 + kb + n] = t[r][n];
    }
}

// ---------------- MFMA GEMM, BK=64, XOR-swizzled DMA staging ----------------
// A: [8192][K] bf16, Bt: [N][K] bf16. 128x128 tile, 256 thr = 4 waves 2x2.
// MODE 0: fused QKV, N=2048, grid 1024 (4-5 blocks/CU): single-buffer loop --
//   implicit wave-level overlap covers the DMA drain (m99/m100: dbuf neutral).
// MODE 1: out-proj, N=1024, grid 512 = only 2 blocks/CU: no implicit overlap,
//   so use T3 2-phase double-buffer (prefetch t+1 before compute t). LDS 64 KB
//   is free here (2 blocks/CU is grid-limited anyway).
template<int MODE>
__global__ __launch_bounds__(256) void gemm_mfma(
    const u16* __restrict__ A, const u16* __restrict__ Bt,
    const float* __restrict__ b0, const float* __restrict__ b1,
    const float* __restrict__ b2,
    const float* __restrict__ resid, float* __restrict__ Cf,
    u16* __restrict__ Qo, u16* __restrict__ Ko, u16* __restrict__ Vto,
    int N, int K)
{
    constexpr int NBUF = (MODE == 1) ? 2 : 1;
    __shared__ __align__(16) u16 Asl[NBUF][128 * 64];
    __shared__ __align__(16) u16 Bsl[NBUF][128 * 64];
    const int tid = threadIdx.x, lane = tid & 63, w = tid >> 6;
    const int quad = lane >> 4, l16 = lane & 15;
    const int bm = blockIdx.y * 128, bn = blockIdx.x * 128;
    const int wm = (w >> 1) * 64, wn = (w & 1) * 64;

    f32x4 acc[4][4] = {};

    const int dr = lane >> 3;                       // row within 8-row band
    const int dcs = (((lane & 7) ^ dr) << 3);       // swizzled global chunk (elems)
    const u16* Ag = &A[(size_t)(bm + w * 32 + dr) * K + dcs];
    const u16* Bg = &Bt[(size_t)(bn + w * 32 + dr) * K + dcs];

    const int sw = l16 & 7;  // fragment-read swizzle

    if constexpr (MODE == 1) {
        // ---- 2-phase pipelined loop (double-buffered) ----
        const int NT = K >> 6;
#pragma unroll
        for (int c = 0; c < 4; ++c) {  // prologue: stage tile 0 -> buf 0
            gll16(Ag + (size_t)(c * 8) * K, &Asl[0][(w * 32 + c * 8) * 64]);
            gll16(Bg + (size_t)(c * 8) * K, &Bsl[0][(w * 32 + c * 8) * 64]);
        }
        for (int t = 0; t < NT; ++t) {
            const int cur = t & 1;
            // drains this wave's outstanding DMA (tile t, issued during the
            // previous tile's compute) + barrier -> tile t staged everywhere.
            __syncthreads();
            if (t < NT - 1) {
                const int k0 = (t + 1) * 64;
#pragma unroll
                for (int c = 0; c < 4; ++c) {
                    gll16(Ag + (size_t)(c * 8) * K + k0, &Asl[cur ^ 1][(w * 32 + c * 8) * 64]);
                    gll16(Bg + (size_t)(c * 8) * K + k0, &Bsl[cur ^ 1][(w * 32 + c * 8) * 64]);
                }
            }
            bf16x8 af[4][2], bfr[4][2];
#pragma unroll
            for (int i = 0; i < 4; ++i)
#pragma unroll
                for (int ks = 0; ks < 2; ++ks)
                    af[i][ks] = *(const bf16x8*)&Asl[cur][(wm + i * 16 + l16) * 64 + (((ks * 4 + quad) ^ sw) << 3)];
#pragma unroll
            for (int j = 0; j < 4; ++j)
#pragma unroll
                for (int ks = 0; ks < 2; ++ks)
                    bfr[j][ks] = *(const bf16x8*)&Bsl[cur][(wn + j * 16 + l16) * 64 + (((ks * 4 + quad) ^ sw) << 3)];
#pragma unroll
            for (int i = 0; i < 4; ++i)
#pragma unroll
                for (int j = 0; j < 4; ++j)
#pragma unroll
                    for (int ks = 0; ks < 2; ++ks)
                        acc[i][j] = __builtin_amdgcn_mfma_f32_16x16x32_bf16(af[i][ks], bfr[j][ks], acc[i][j], 0, 0, 0);
            // no trailing barrier: next iteration's __syncthreads covers the
            // read-before-overwrite hazard (prefetch targets the other buffer).
        }
    } else {
        // ---- single-buffer loop (4-5 blocks/CU: implicit overlap) ----
        for (int k0 = 0; k0 < K; k0 += 64) {
#pragma unroll
            for (int c = 0; c < 4; ++c) {
                gll16(Ag + (size_t)(c * 8) * K + k0, &Asl[0][(w * 32 + c * 8) * 64]);
                gll16(Bg + (size_t)(c * 8) * K + k0, &Bsl[0][(w * 32 + c * 8) * 64]);
            }
            __syncthreads();   // drains vmcnt -> staged data visible
            bf16x8 af[4][2], bfr[4][2];
#pragma unroll
            for (int i = 0; i < 4; ++i)
#pragma unroll
                for (int ks = 0; ks < 2; ++ks)
                    af[i][ks] = *(const bf16x8*)&Asl[0][(wm + i * 16 + l16) * 64 + (((ks * 4 + quad) ^ sw) << 3)];
#pragma unroll
            for (int j = 0; j < 4; ++j)
#pragma unroll
                for (int ks = 0; ks < 2; ++ks)
                    bfr[j][ks] = *(const bf16x8*)&Bsl[0][(wn + j * 16 + l16) * 64 + (((ks * 4 + quad) ^ sw) << 3)];
#pragma unroll
            for (int i = 0; i < 4; ++i)
#pragma unroll
                for (int j = 0; j < 4; ++j)
#pragma unroll
                    for (int ks = 0; ks < 2; ++ks)
                        acc[i][j] = __builtin_amdgcn_mfma_f32_16x16x32_bf16(af[i][ks], bfr[j][ks], acc[i][j], 0, 0, 0);
            __syncthreads();   // LDS reads done before next stage overwrites
        }
    }

    // epilogue: C/D layout col=lane&15, row=quad*4+reg
#pragma unroll
    for (int j = 0; j < 4; ++j) {
        int col = bn + wn + j * 16 + l16;
        if (MODE == 1) {
            float bb = b0[col];
#pragma unroll
            for (int i = 0; i < 4; ++i) {
                int row0 = bm + wm + i * 16 + quad * 4;
#pragma unroll
                for (int r = 0; r < 4; ++r) {
                    size_t off = (size_t)(row0 + r) * N + col;
                    Cf[off] = acc[i][j][r] + bb + resid[off];
                }
            }
        } else if (col < 1024) {
            float bb = b0[col];
#pragma unroll
            for (int i = 0; i < 4; ++i) {
                int row0 = bm + wm + i * 16 + quad * 4;
#pragma unroll
                for (int r = 0; r < 4; ++r)
                    Qo[(size_t)(row0 + r) * 1024 + col] = f2bf(acc[i][j][r] + bb);
            }
        } else if (col < 1536) {
            int c2 = col - 1024;
            float bb = b1[c2];
#pragma unroll
            for (int i = 0; i < 4; ++i) {
                int row0 = bm + wm + i * 16 + quad * 4;
#pragma unroll
                for (int r = 0; r < 4; ++r)
                    Ko[(size_t)(row0 + r) * 512 + c2] = f2bf(acc[i][j][r] + bb);
            }
        } else {
            int c2 = col - 1536, kvh = c2 >> 6, d = c2 & 63;
            float bb = b2[c2];
#pragma unroll
            for (int i = 0; i < 4; ++i) {
                int row0 = bm + wm + i * 16 + quad * 4;
                int b = row0 >> 10, s = row0 & 1023;
                ushort4 o4;
                o4.x = f2bf(acc[i][j][0] + bb);
                o4.y = f2bf(acc[i][j][1] + bb);
                o4.z = f2bf(acc[i][j][2] + bb);
                o4.w = f2bf(acc[i][j][3] + bb);
                *(ushort4*)&Vto[(size_t)((b * 8 + kvh) * 64 + d) * 1024 + s] = o4;
            }
        }
    }
}

// ---------------- RoPE (interleaved), in place on bf16 (K only) ----------------
__global__ __launch_bounds__(256) void rope_bf16_kernel(
    u16* __restrict__ x, int shift, int stride, int total)
{
    int idx = blockIdx.x * 256 + threadIdx.x;
    if (idx >= total) return;
    int j = idx & 31;
    int h = (idx >> 5) & ((1 << shift) - 1);
    int row = idx >> (5 + shift);
    int pos = row & 1023;
    float inv = exp2f((float)j * -0.4152410118609203f);  // 10000^(-2j/64)
    float sn, cs;
    sincosf((float)pos * inv, &sn, &cs);
    unsigned* p = (unsigned*)&x[(size_t)row * stride + h * 64 + (j << 1)];
    unsigned u = *p;
    float x1 = bf2f((u16)(u & 0xffff)), x2 = bf2f((u16)(u >> 16));
    float y1 = x1 * cs - x2 * sn, y2 = x1 * sn + x2 * cs;
    *p = (unsigned)f2bf(y1) | ((unsigned)f2bf(y2) << 16);
}

// ---------------- MFMA flash attention: 128 q/block, fused Q-RoPE ----------------
// Q: [8192][1024] bf16 (h*64+d, UNroped). K: [8192][512] (kvh*64+d, roped).
// Vt: [(b*8+kvh)*64+d][1024 keys] bf16 (pre-transposed).
// Pipelined: double-buffered Ks/Vts (T3 2-phase); one __syncthreads per tile
// (its vmcnt(0) drain is exactly tile kt's DMA, in flight during kt-1 compute).
// Ps shrunk to [64][40]: PV is q-group-serial with V fragments cached in regs,
// so each wave time-shares a 16-row Ps band (in-wave LDS ordering, no barrier).
// LDS 37.9 KB -> 4 blocks/CU; grid 1024 = 256 CU x 4 -> fully co-resident.
// XCD-chunked swizzle: hardware id%8 = XCD; nid = (id&7)*128 + (id>>3) puts
// each batch b (K+V 2.1 MB, fits 4 MB L2) on exactly one XCD.
// T5 setprio wrapped around MFMA clusters (phase-diverse waves, m191 +4-7%).
__global__ __launch_bounds__(256, 4) void attn_mfma(
    const u16* __restrict__ Q, const u16* __restrict__ K,
    const u16* __restrict__ Vt, u16* __restrict__ O)
{
    __shared__ __align__(16) u16 Ks[2][64 * 64];   // [buf][key][d], swizzled chunks
    __shared__ __align__(16) u16 Vts[2][64 * 64];  // [buf][d][key], swizzled chunks
    __shared__ __align__(16) u16 Ps[64][40];       // [wave 16-row band][32 keys + pad]

    const int tid = threadIdx.x, lane = tid & 63, w = tid >> 6;
    const int quad = lane >> 4, l16 = lane & 15;
    const int id = blockIdx.x;
    const int nid = (id & 7) * 128 + (id >> 3);    // XCD-chunked (id%8 -> XCD)
    const int qt = nid & 7, h = (nid >> 3) & 15, b = nid >> 7;
    const int kvh = h >> 1;
    const size_t qrow0 = (size_t)b * 1024 + qt * 128;
    const size_t krow0 = (size_t)b * 1024;
    const u16* Vg = Vt + (size_t)((b * 8 + kvh) * 64) * 1024;

    // DMA staging: per wave 16 rows each of K,V^T; 2 calls of 8 rows each.
    const int dr = lane >> 3;                    // row in 8-row band
    const int dcs = (((lane & 7) ^ dr) << 3);    // swizzled global chunk (elems)
    const u16* Kg0 = &K[(krow0 + w * 16 + dr) * 512 + kvh * 64 + dcs];
    const u16* Vg0 = &Vg[(size_t)(w * 16 + dr) * 1024 + dcs];
    const int sw = l16 & 7;
    const float C1 = 0.18033688011112043f;  // 0.125 * log2(e), folded into Q

    // prologue: stage tile 0 into buffer 0 (overlaps Q-RoPE prep below)
#pragma unroll
    for (int c = 0; c < 2; ++c) {
        gll16(Kg0 + (size_t)(c * 8) * 512, &Ks[0][(w * 16 + c * 8) * 64]);
        gll16(Vg0 + (size_t)(c * 8) * 1024, &Vts[0][(w * 16 + c * 8) * 64]);
    }

    // Q fragments with RoPE (and softmax scale C1) applied in-register.
    // B-operand layout: lane holds q, d = ks*32 + quad*8 + (0..7); pairs (2j,2j+1)
    // are in-lane: u32 slot t of the uint4 holds pair j = ks*16 + quad*4 + t.
    bf16x8 qf[2][2];
#pragma unroll
    for (int qg = 0; qg < 2; ++qg) {
        int qrow = w * 32 + qg * 16 + l16;
        float fpos = (float)(qt * 128 + qrow);
#pragma unroll
        for (int ks = 0; ks < 2; ++ks) {
            uint4 qraw = *(const uint4*)&Q[(qrow0 + qrow) * 1024 + h * 64 + ks * 32 + quad * 8];
            unsigned o_[4];
#pragma unroll
            for (int t = 0; t < 4; ++t) {
                int j = ks * 16 + quad * 4 + t;
                float inv = exp2f((float)j * -0.4152410118609203f);
                float sn_, cs_;
                sincosf(fpos * inv, &sn_, &cs_);
                cs_ *= C1; sn_ *= C1;            // fold softmax scale into Q
                unsigned u = (&qraw.x)[t];
                float x1 = bf2f((u16)(u & 0xffff)), x2 = bf2f((u16)(u >> 16));
                float y1 = x1 * cs_ - x2 * sn_, y2 = x1 * sn_ + x2 * cs_;
                o_[t] = (unsigned)f2bf(y1) | ((unsigned)f2bf(y2) << 16);
            }
            qf[qg][ks] = __builtin_bit_cast(bf16x8, make_uint4(o_[0], o_[1], o_[2], o_[3]));
        }
    }

    f32x4 acc_o[2][4] = {};
    f32x4 lsum[2] = {};  // ones-MFMA row-sum accumulator (all regs equal at end)
    const bf16x8 ones = __builtin_bit_cast(bf16x8,
        make_uint4(0x3F803F80u, 0x3F803F80u, 0x3F803F80u, 0x3F803F80u));

    for (int kt = 0; kt < 16; ++kt) {
        const int cur = kt & 1;
        // drains this wave's outstanding DMA (tile kt, in flight during the
        // previous tile's compute) + barrier -> tile kt staged everywhere.
        __syncthreads();

        // prefetch tile kt+1 into the other buffer; its last reader was
        // compute(kt-1), which precedes this barrier for all waves.
        if (kt < 15) {
#pragma unroll
            for (int c = 0; c < 2; ++c) {
                gll16(Kg0 + (size_t)((kt + 1) * 64 + c * 8) * 512,
                      &Ks[cur ^ 1][(w * 16 + c * 8) * 64]);
                gll16(Vg0 + (size_t)(c * 8) * 1024 + (kt + 1) * 64,
                      &Vts[cur ^ 1][(w * 16 + c * 8) * 64]);
            }
        }

        // S^T = K . Q^T : s[qg][nt] holds keys nt*16+quad*4+(0..3) for q-group qg
        f32x4 s[2][4] = {};
        __builtin_amdgcn_s_setprio(1);
#pragma unroll
        for (int ks = 0; ks < 2; ++ks) {
#pragma unroll
            for (int nt = 0; nt < 4; ++nt) {
                bf16x8 ak = *(const bf16x8*)&Ks[cur][(nt * 16 + l16) * 64 + (((ks * 4 + quad) ^ sw) << 3)];
                s[0][nt] = __builtin_amdgcn_mfma_f32_16x16x32_bf16(ak, qf[0][ks], s[0][nt], 0, 0, 0);
                s[1][nt] = __builtin_amdgcn_mfma_f32_16x16x32_bf16(ak, qf[1][ks], s[1][nt], 0, 0, 0);
            }
        }
        __builtin_amdgcn_s_setprio(0);

        // per key-chunk kc (keys kc*32..+31): softmax -> Ps band, then PV MFMA.
        // Ps band is wave-private AND time-shared across (kc, qg): in-wave LDS
        // ordering guarantees qg0's read completes before qg1's overwrite.
#pragma unroll
        for (int kc = 0; kc < 2; ++kc) {
            bf16x8 av[4];  // V fragments cached: shared by both q-groups
#pragma unroll
            for (int nt = 0; nt < 4; ++nt)
                av[nt] = *(const bf16x8*)&Vts[cur][(nt * 16 + l16) * 64 + (((kc * 4 + quad) ^ sw) << 3)];
#pragma unroll
            for (int qg = 0; qg < 2; ++qg) {
#pragma unroll
                for (int ntl = 0; ntl < 2; ++ntl) {
                    int nt = kc * 2 + ntl;
                    float p0 = __builtin_amdgcn_exp2f(s[qg][nt][0]);
                    float p1 = __builtin_amdgcn_exp2f(s[qg][nt][1]);
                    unsigned pk0 = __builtin_amdgcn_perm(
                        __builtin_bit_cast(unsigned, p1),
                        __builtin_bit_cast(unsigned, p0), 0x07060302u);
                    float p2 = __builtin_amdgcn_exp2f(s[qg][nt][2]);
                    float p3 = __builtin_amdgcn_exp2f(s[qg][nt][3]);
                    unsigned pk1 = __builtin_amdgcn_perm(
                        __builtin_bit_cast(unsigned, p3),
                        __builtin_bit_cast(unsigned, p2), 0x07060302u);
                    *(uint2*)&Ps[w * 16 + l16][ntl * 16 + quad * 4] = make_uint2(pk0, pk1);
                }
                bf16x8 bp = *(const bf16x8*)&Ps[w * 16 + l16][quad * 8];
                __builtin_amdgcn_s_setprio(1);
                // l_i = P . 1 via ones-MFMA (sums the exact bf16 P used by PV)
                lsum[qg] = __builtin_amdgcn_mfma_f32_16x16x32_bf16(ones, bp, lsum[qg], 0, 0, 0);
                // O^T += V^T(chunk kc) . P^T(chunk kc)
#pragma unroll
                for (int nt = 0; nt < 4; ++nt)
                    acc_o[qg][nt] = __builtin_amdgcn_mfma_f32_16x16x32_bf16(av[nt], bp, acc_o[qg][nt], 0, 0, 0);
                __builtin_amdgcn_s_setprio(0);
            }
        }
        // no trailing barrier: next iteration's __syncthreads covers the
        // read-before-overwrite hazard (prefetch targets the other buffer).
    }

    // epilogue: lsum already holds full row sums (all lanes/regs for q=l16)
#pragma unroll
    for (int qg = 0; qg < 2; ++qg) {
        float rl = 1.0f / lsum[qg][0];
        size_t orow = (qrow0 + w * 32 + qg * 16 + l16) * 1024 + h * 64;
#pragma unroll
        for (int nt = 0; nt < 4; ++nt) {
            ushort4 o4;
            o4.x = f2bf(acc_o[qg][nt][0] * rl);
            o4.y = f2bf(acc_o[qg][nt][1] * rl);
            o4.z = f2bf(acc_o[qg][nt][2] * rl);
            o4.w = f2bf(acc_o[qg][nt][3] * rl);
            *(ushort4*)&O[orow + nt * 16 + quad * 4] = o4;
        }
    }
}

// ---------------- LayerNorm in place on [8192][1024] fp32 ----------------
__global__ __launch_bounds__(256) void ln_kernel(float* __restrict__ io,
    const float* __restrict__ gamma, const float* __restrict__ beta)
{
    int row = blockIdx.x;
    int tid = threadIdx.x;
    float* p = io + (size_t)row * 1024;
    float4 x = *reinterpret_cast<const float4*>(&p[tid << 2]);
    float s = x.x + x.y + x.z + x.w;
    float ss = fmaf(x.x, x.x, fmaf(x.y, x.y, fmaf(x.z, x.z, x.w * x.w)));
#pragma unroll
    for (int off = 32; off > 0; off >>= 1) {
        s  += __shfl_down(s, off);
        ss += __shfl_down(ss, off);
    }
    __shared__ float rs[4], rss[4];
    int lane = tid & 63, wid = tid >> 6;
    if (lane == 0) { rs[wid] = s; rss[wid] = ss; }
    __syncthreads();
    float S = rs[0] + rs[1] + rs[2] + rs[3];
    float SS = rss[0] + rss[1] + rss[2] + rss[3];
    float mu = S * (1.0f / 1024.0f);
    float var = SS * (1.0f / 1024.0f) - mu * mu;
    float rstd = rsqrtf(var + 1e-12f);
    float4 g = *reinterpret_cast<const float4*>(&gamma[tid << 2]);
    float4 be = *reinterpret_cast<const float4*>(&beta[tid << 2]);
    float4 o;
    o.x = (x.x - mu) * rstd * g.x + be.x;
    o.y = (x.y - mu) * rstd * g.y + be.y;
    o.z = (x.z - mu) * rstd * g.z + be.z;
    o.w = (x.w - mu) * rstd * g.w + be.w;
    *reinterpret_cast<float4*>(&p[tid << 2]) = o;
}

// ---------------- launch ----------------
extern "C" void kernel_launch(void* const* d_in, const int* in_sizes, int n_in,
                              void* d_out, int out_size, void* d_ws, size_t ws_size,
                              hipStream_t stream)
{
    (void)in_sizes; (void)n_in; (void)out_size; (void)ws_size;
    const float* hidden = (const float*)d_in[0];
    const float* Wq = (const float*)d_in[1];
    const float* bq = (const float*)d_in[2];
    const float* Wk = (const float*)d_in[3];
    const float* bk = (const float*)d_in[4];
    const float* Wv = (const float*)d_in[5];
    const float* bv = (const float*)d_in[6];
    const float* Wo = (const float*)d_in[7];
    const float* bo = (const float*)d_in[8];
    const float* g  = (const float*)d_in[9];
    const float* be = (const float*)d_in[10];
    float* out = (float*)d_out;

    // workspace layout (Wqt/Wkt/Wvt contiguous => one [2048][1024] B^T matrix)
    u16* hb  = (u16*)d_ws;                       // [8192][1024] bf16 hidden
    u16* Wqt = hb  + (size_t)8192 * 1024;        // [1024][1024] Wq^T
    u16* Wkt = Wqt + (size_t)1024 * 1024;        // [512][1024]  Wk^T
    u16* Wvt = Wkt + (size_t)512 * 1024;         // [512][1024]  Wv^T
    u16* Wot = Wvt + (size_t)512 * 1024;         // [1024][1024] Wo^T
    u16* Qb  = Wot + (size_t)1024 * 1024;        // [8192][1024] Q (then attn out)
    u16* Kb  = Qb  + (size_t)8192 * 1024;        // [8192][512]  K
    u16* Vtb = Kb  + (size_t)8192 * 512;         // [4096][1024] V^T per (b,kvh)
    // total ~66 MB

    cvt_bf16_kernel<<<8192, 256, 0, stream>>>(hidden, hb, 8192 * 1024 / 4);
    cvt_t4_kernel<<<dim3(16, 16, 4), 256, 0, stream>>>(Wq, Wk, Wv, Wo, Wqt, Wkt, Wvt, Wot);

    // fused QKV: N=2048 (Bt = [Wq^T;Wk^T;Wv^T]), writes Qb (unroped), Kb, Vtb (V transposed)
    gemm_mfma<0><<<dim3(16, 64), 256, 0, stream>>>(hb, Wqt, bq, bk, bv,
        nullptr, nullptr, Qb, Kb, Vtb, 2048, 1024);

    // RoPE on K only (Q roped inside attn)
    rope_bf16_kernel<<<8192, 256, 0, stream>>>(Kb, 3, 512, 8192 * 8 * 32);

    attn_mfma<<<dim3(1024), 256, 0, stream>>>(Qb, Kb, Vtb, Qb);

    // out-proj: fp32 out + bias + resid, 2-phase pipelined
    gemm_mfma<1><<<dim3(8, 64), 256, 0, stream>>>(Qb, Wot, bo, nullptr, nullptr,
        hidden, out, nullptr, nullptr, nullptr, 1024, 1024);
    ln_kernel<<<8192, 256, 0, stream>>>(out, g, be);
}

// Round 4
// 235.447 us; speedup vs baseline: 1.1451x; 1.0393x over previous
//
#include <hip/hip_runtime.h>
#include <math.h>
#include <stdint.h>

typedef unsigned short u16;
typedef __bf16 bf16x8 __attribute__((ext_vector_type(8)));
typedef float f32x4 __attribute__((ext_vector_type(4)));

typedef const __attribute__((address_space(1))) void gv_t;
typedef __attribute__((address_space(3))) void lv_t;

__device__ __forceinline__ u16 f2bf(float f) {
    unsigned u = __builtin_bit_cast(unsigned, f);
    return (u16)((u + 0x7FFFu + ((u >> 16) & 1u)) >> 16);
}
__device__ __forceinline__ float bf2f(u16 h) {
    return __builtin_bit_cast(float, (unsigned)h << 16);
}
// async global->LDS, 16B per lane; LDS dest = wave-uniform base + lane*16
__device__ __forceinline__ void gll16(const void* g, void* l) {
    __builtin_amdgcn_global_load_lds((gv_t*)(uintptr_t)g,
                                     (lv_t*)(unsigned)(uintptr_t)l, 16, 0, 0);
}

// ---------------- fp32 -> bf16 elementwise ----------------
__global__ __launch_bounds__(256) void cvt_bf16_kernel(
    const float* __restrict__ in, u16* __restrict__ out, int n4)
{
    int i = blockIdx.x * 256 + threadIdx.x;
    if (i >= n4) return;
    float4 f = ((const float4*)in)[i];
    ushort4 o = make_ushort4(f2bf(f.x), f2bf(f.y), f2bf(f.z), f2bf(f.w));
    ((ushort4*)out)[i] = o;
}

// ---------------- all 4 weights: fp32 [1024][N] -> bf16 [N][1024] ----------------
__global__ __launch_bounds__(256) void cvt_t4_kernel(
    const float* __restrict__ w0, const float* __restrict__ w1,
    const float* __restrict__ w2, const float* __restrict__ w3,
    u16* __restrict__ o0, u16* __restrict__ o1,
    u16* __restrict__ o2, u16* __restrict__ o3)
{
    __shared__ u16 t[64][65];
    const float* in; u16* out; int N;
    switch (blockIdx.z) {
        case 0: in = w0; out = o0; N = 1024; break;
        case 1: in = w1; out = o1; N = 512;  break;
        case 2: in = w2; out = o2; N = 512;  break;
        default: in = w3; out = o3; N = 1024; break;
    }
    int kb = blockIdx.y * 64, nb = blockIdx.x * 64;
    if (nb >= N) return;
    int tid = threadIdx.x;
#pragma unroll
    for (int c = 0; c < 16; ++c) {
        int id = c * 256 + tid;
        int r = id >> 6, n = id & 63;
        t[n][r] = f2bf(in[(size_t)(kb + r) * N + nb + n]);
    }
    __syncthreads();
#pragma unroll
    for (int c = 0; c < 16; ++c) {
        int id = c * 256 + tid;
        int r = id >> 6, n = id & 63;
        out[(size_t)(nb + r) * 1024 + kb + n] = t[r][n];
    }
}

// ---------------- MFMA GEMM body, BK=64, 2-phase dbuf, XOR-swizzled DMA -----
// A: [8192][K] bf16, Bt: [N][K] bf16. 128x128 tile, 256 thr = 4 waves 2x2.
// Unified T3 2-phase pipeline (proven on attn R1 and out-proj R2->R3):
// prologue stages tile 0; per tile: __syncthreads (drains tile t's DMA, which
// flew during tile t-1's compute) -> issue t+1 -> ds_read + MFMA. LDS 64 KB
// -> 2 blocks/CU (grid-matched for out-proj; 2 shots for QKV).
// XCD-chunked remap: hw id%8 = XCD; contiguous nid chunk per XCD so the
// blocks sharing A-panels co-locate with the B panel in one 4 MiB L2.
// MODE 0: fused QKV, N=2048. cols 0-1023 -> Qo (bias b0, unroped);
//   1024-1535 -> Ko (stride 512, bias b1); 1536-2047 -> V transposed to
//   Vto[((b*8+kvh)*64+d)*1024+s] (bias b2), packed ushort4 along s.
// MODE 1: N=1024, fp32 out Cf = acc + b0 + resid.
template<int MODE, int NBX>
__device__ __forceinline__ void gemm_body(
    const u16* __restrict__ A, const u16* __restrict__ Bt,
    const float* __restrict__ b0, const float* __restrict__ b1,
    const float* __restrict__ b2,
    const float* __restrict__ resid, float* __restrict__ Cf,
    u16* __restrict__ Qo, u16* __restrict__ Ko, u16* __restrict__ Vto,
    int N, int K)
{
    __shared__ __align__(16) u16 Asl[2][128 * 64];
    __shared__ __align__(16) u16 Bsl[2][128 * 64];
    const int tid = threadIdx.x, lane = tid & 63, w = tid >> 6;
    const int quad = lane >> 4, l16 = lane & 15;
    const int id = blockIdx.x;
    const int chunk = (NBX * 64) >> 3;                // blocks per XCD
    const int nid = (id & 7) * chunk + (id >> 3);     // id%8 -> XCD
    const int bx = nid & (NBX - 1), by = nid / NBX;
    const int bm = by * 128, bn = bx * 128;
    const int wm = (w >> 1) * 64, wn = (w & 1) * 64;

    f32x4 acc[4][4] = {};

    const int dr = lane >> 3;                       // row within 8-row band
    const int dcs = (((lane & 7) ^ dr) << 3);       // swizzled global chunk (elems)
    const u16* Ag = &A[(size_t)(bm + w * 32 + dr) * K + dcs];
    const u16* Bg = &Bt[(size_t)(bn + w * 32 + dr) * K + dcs];

    const int sw = l16 & 7;  // fragment-read swizzle

    const int NT = K >> 6;
#pragma unroll
    for (int c = 0; c < 4; ++c) {  // prologue: stage tile 0 -> buf 0
        gll16(Ag + (size_t)(c * 8) * K, &Asl[0][(w * 32 + c * 8) * 64]);
        gll16(Bg + (size_t)(c * 8) * K, &Bsl[0][(w * 32 + c * 8) * 64]);
    }
    for (int t = 0; t < NT; ++t) {
        const int cur = t & 1;
        // drains this wave's outstanding DMA (tile t, issued during the
        // previous tile's compute) + barrier -> tile t staged everywhere.
        __syncthreads();
        if (t < NT - 1) {
            const int k0 = (t + 1) * 64;
#pragma unroll
            for (int c = 0; c < 4; ++c) {
                gll16(Ag + (size_t)(c * 8) * K + k0, &Asl[cur ^ 1][(w * 32 + c * 8) * 64]);
                gll16(Bg + (size_t)(c * 8) * K + k0, &Bsl[cur ^ 1][(w * 32 + c * 8) * 64]);
            }
        }
        bf16x8 af[4][2], bfr[4][2];
#pragma unroll
        for (int i = 0; i < 4; ++i)
#pragma unroll
            for (int ks = 0; ks < 2; ++ks)
                af[i][ks] = *(const bf16x8*)&Asl[cur][(wm + i * 16 + l16) * 64 + (((ks * 4 + quad) ^ sw) << 3)];
#pragma unroll
        for (int j = 0; j < 4; ++j)
#pragma unroll
            for (int ks = 0; ks < 2; ++ks)
                bfr[j][ks] = *(const bf16x8*)&Bsl[cur][(wn + j * 16 + l16) * 64 + (((ks * 4 + quad) ^ sw) << 3)];
#pragma unroll
        for (int i = 0; i < 4; ++i)
#pragma unroll
            for (int j = 0; j < 4; ++j)
#pragma unroll
                for (int ks = 0; ks < 2; ++ks)
                    acc[i][j] = __builtin_amdgcn_mfma_f32_16x16x32_bf16(af[i][ks], bfr[j][ks], acc[i][j], 0, 0, 0);
        // no trailing barrier: next iteration's __syncthreads covers the
        // read-before-overwrite hazard (prefetch targets the other buffer).
    }

    // epilogue: C/D layout col=lane&15, row=quad*4+reg
#pragma unroll
    for (int j = 0; j < 4; ++j) {
        int col = bn + wn + j * 16 + l16;
        if (MODE == 1) {
            float bb = b0[col];
#pragma unroll
            for (int i = 0; i < 4; ++i) {
                int row0 = bm + wm + i * 16 + quad * 4;
#pragma unroll
                for (int r = 0; r < 4; ++r) {
                    size_t off = (size_t)(row0 + r) * N + col;
                    Cf[off] = acc[i][j][r] + bb + resid[off];
                }
            }
        } else if (col < 1024) {
            float bb = b0[col];
#pragma unroll
            for (int i = 0; i < 4; ++i) {
                int row0 = bm + wm + i * 16 + quad * 4;
#pragma unroll
                for (int r = 0; r < 4; ++r)
                    Qo[(size_t)(row0 + r) * 1024 + col] = f2bf(acc[i][j][r] + bb);
            }
        } else if (col < 1536) {
            int c2 = col - 1024;
            float bb = b1[c2];
#pragma unroll
            for (int i = 0; i < 4; ++i) {
                int row0 = bm + wm + i * 16 + quad * 4;
#pragma unroll
                for (int r = 0; r < 4; ++r)
                    Ko[(size_t)(row0 + r) * 512 + c2] = f2bf(acc[i][j][r] + bb);
            }
        } else {
            int c2 = col - 1536, kvh = c2 >> 6, d = c2 & 63;
            float bb = b2[c2];
#pragma unroll
            for (int i = 0; i < 4; ++i) {
                int row0 = bm + wm + i * 16 + quad * 4;
                int b = row0 >> 10, s = row0 & 1023;
                ushort4 o4;
                o4.x = f2bf(acc[i][j][0] + bb);
                o4.y = f2bf(acc[i][j][1] + bb);
                o4.z = f2bf(acc[i][j][2] + bb);
                o4.w = f2bf(acc[i][j][3] + bb);
                *(ushort4*)&Vto[(size_t)((b * 8 + kvh) * 64 + d) * 1024 + s] = o4;
            }
        }
    }
}

// Distinct kernel names so rocprof rows are unambiguous per mode.
__global__ __launch_bounds__(256) void gemm_qkv(
    const u16* __restrict__ A, const u16* __restrict__ Bt,
    const float* __restrict__ b0, const float* __restrict__ b1,
    const float* __restrict__ b2,
    u16* __restrict__ Qo, u16* __restrict__ Ko, u16* __restrict__ Vto)
{
    gemm_body<0, 16>(A, Bt, b0, b1, b2, nullptr, nullptr, Qo, Ko, Vto, 2048, 1024);
}

__global__ __launch_bounds__(256) void gemm_out(
    const u16* __restrict__ A, const u16* __restrict__ Bt,
    const float* __restrict__ b0,
    const float* __restrict__ resid, float* __restrict__ Cf)
{
    gemm_body<1, 8>(A, Bt, b0, nullptr, nullptr, resid, Cf,
                    nullptr, nullptr, nullptr, 1024, 1024);
}

// ---------------- RoPE (interleaved), in place on bf16 (K only) ----------------
__global__ __launch_bounds__(256) void rope_bf16_kernel(
    u16* __restrict__ x, int shift, int stride, int total)
{
    int idx = blockIdx.x * 256 + threadIdx.x;
    if (idx >= total) return;
    int j = idx & 31;
    int h = (idx >> 5) & ((1 << shift) - 1);
    int row = idx >> (5 + shift);
    int pos = row & 1023;
    float inv = exp2f((float)j * -0.4152410118609203f);  // 10000^(-2j/64)
    float sn, cs;
    sincosf((float)pos * inv, &sn, &cs);
    unsigned* p = (unsigned*)&x[(size_t)row * stride + h * 64 + (j << 1)];
    unsigned u = *p;
    float x1 = bf2f((u16)(u & 0xffff)), x2 = bf2f((u16)(u >> 16));
    float y1 = x1 * cs - x2 * sn, y2 = x1 * sn + x2 * cs;
    *p = (unsigned)f2bf(y1) | ((unsigned)f2bf(y2) << 16);
}

// ---------------- MFMA flash attention: 128 q/block, fused Q-RoPE ----------------
// Q: [8192][1024] bf16 (h*64+d, UNroped). K: [8192][512] (kvh*64+d, roped).
// Vt: [(b*8+kvh)*64+d][1024 keys] bf16 (pre-transposed).
// Pipelined: double-buffered Ks/Vts (T3 2-phase); one __syncthreads per tile
// (its vmcnt(0) drain is exactly tile kt's DMA, in flight during kt-1 compute).
// Ps shrunk to [64][40]: PV is q-group-serial with V fragments cached in regs,
// so each wave time-shares a 16-row Ps band (in-wave LDS ordering, no barrier).
// LDS 37.9 KB -> 4 blocks/CU; grid 1024 = 256 CU x 4 -> fully co-resident.
// XCD-chunked swizzle: hardware id%8 = XCD; nid = (id&7)*128 + (id>>3) puts
// each batch b (K+V 2.1 MB, fits 4 MB L2) on exactly one XCD.
// T5 setprio wrapped around MFMA clusters (phase-diverse waves, m191 +4-7%).
__global__ __launch_bounds__(256, 4) void attn_mfma(
    const u16* __restrict__ Q, const u16* __restrict__ K,
    const u16* __restrict__ Vt, u16* __restrict__ O)
{
    __shared__ __align__(16) u16 Ks[2][64 * 64];   // [buf][key][d], swizzled chunks
    __shared__ __align__(16) u16 Vts[2][64 * 64];  // [buf][d][key], swizzled chunks
    __shared__ __align__(16) u16 Ps[64][40];       // [wave 16-row band][32 keys + pad]

    const int tid = threadIdx.x, lane = tid & 63, w = tid >> 6;
    const int quad = lane >> 4, l16 = lane & 15;
    const int id = blockIdx.x;
    const int nid = (id & 7) * 128 + (id >> 3);    // XCD-chunked (id%8 -> XCD)
    const int qt = nid & 7, h = (nid >> 3) & 15, b = nid >> 7;
    const int kvh = h >> 1;
    const size_t qrow0 = (size_t)b * 1024 + qt * 128;
    const size_t krow0 = (size_t)b * 1024;
    const u16* Vg = Vt + (size_t)((b * 8 + kvh) * 64) * 1024;

    // DMA staging: per wave 16 rows each of K,V^T; 2 calls of 8 rows each.
    const int dr = lane >> 3;                    // row in 8-row band
    const int dcs = (((lane & 7) ^ dr) << 3);    // swizzled global chunk (elems)
    const u16* Kg0 = &K[(krow0 + w * 16 + dr) * 512 + kvh * 64 + dcs];
    const u16* Vg0 = &Vg[(size_t)(w * 16 + dr) * 1024 + dcs];
    const int sw = l16 & 7;
    const float C1 = 0.18033688011112043f;  // 0.125 * log2(e), folded into Q

    // prologue: stage tile 0 into buffer 0 (overlaps Q-RoPE prep below)
#pragma unroll
    for (int c = 0; c < 2; ++c) {
        gll16(Kg0 + (size_t)(c * 8) * 512, &Ks[0][(w * 16 + c * 8) * 64]);
        gll16(Vg0 + (size_t)(c * 8) * 1024, &Vts[0][(w * 16 + c * 8) * 64]);
    }

    // Q fragments with RoPE (and softmax scale C1) applied in-register.
    // B-operand layout: lane holds q, d = ks*32 + quad*8 + (0..7); pairs (2j,2j+1)
    // are in-lane: u32 slot t of the uint4 holds pair j = ks*16 + quad*4 + t.
    bf16x8 qf[2][2];
#pragma unroll
    for (int qg = 0; qg < 2; ++qg) {
        int qrow = w * 32 + qg * 16 + l16;
        float fpos = (float)(qt * 128 + qrow);
#pragma unroll
        for (int ks = 0; ks < 2; ++ks) {
            uint4 qraw = *(const uint4*)&Q[(qrow0 + qrow) * 1024 + h * 64 + ks * 32 + quad * 8];
            unsigned o_[4];
#pragma unroll
            for (int t = 0; t < 4; ++t) {
                int j = ks * 16 + quad * 4 + t;
                float inv = exp2f((float)j * -0.4152410118609203f);
                float sn_, cs_;
                sincosf(fpos * inv, &sn_, &cs_);
                cs_ *= C1; sn_ *= C1;            // fold softmax scale into Q
                unsigned u = (&qraw.x)[t];
                float x1 = bf2f((u16)(u & 0xffff)), x2 = bf2f((u16)(u >> 16));
                float y1 = x1 * cs_ - x2 * sn_, y2 = x1 * sn_ + x2 * cs_;
                o_[t] = (unsigned)f2bf(y1) | ((unsigned)f2bf(y2) << 16);
            }
            qf[qg][ks] = __builtin_bit_cast(bf16x8, make_uint4(o_[0], o_[1], o_[2], o_[3]));
        }
    }

    f32x4 acc_o[2][4] = {};
    f32x4 lsum[2] = {};  // ones-MFMA row-sum accumulator (all regs equal at end)
    const bf16x8 ones = __builtin_bit_cast(bf16x8,
        make_uint4(0x3F803F80u, 0x3F803F80u, 0x3F803F80u, 0x3F803F80u));

    for (int kt = 0; kt < 16; ++kt) {
        const int cur = kt & 1;
        // drains this wave's outstanding DMA (tile kt, in flight during the
        // previous tile's compute) + barrier -> tile kt staged everywhere.
        __syncthreads();

        // prefetch tile kt+1 into the other buffer; its last reader was
        // compute(kt-1), which precedes this barrier for all waves.
        if (kt < 15) {
#pragma unroll
            for (int c = 0; c < 2; ++c) {
                gll16(Kg0 + (size_t)((kt + 1) * 64 + c * 8) * 512,
                      &Ks[cur ^ 1][(w * 16 + c * 8) * 64]);
                gll16(Vg0 + (size_t)(c * 8) * 1024 + (kt + 1) * 64,
                      &Vts[cur ^ 1][(w * 16 + c * 8) * 64]);
            }
        }

        // S^T = K . Q^T : s[qg][nt] holds keys nt*16+quad*4+(0..3) for q-group qg
        f32x4 s[2][4] = {};
        __builtin_amdgcn_s_setprio(1);
#pragma unroll
        for (int ks = 0; ks < 2; ++ks) {
#pragma unroll
            for (int nt = 0; nt < 4; ++nt) {
                bf16x8 ak = *(const bf16x8*)&Ks[cur][(nt * 16 + l16) * 64 + (((ks * 4 + quad) ^ sw) << 3)];
                s[0][nt] = __builtin_amdgcn_mfma_f32_16x16x32_bf16(ak, qf[0][ks], s[0][nt], 0, 0, 0);
                s[1][nt] = __builtin_amdgcn_mfma_f32_16x16x32_bf16(ak, qf[1][ks], s[1][nt], 0, 0, 0);
            }
        }
        __builtin_amdgcn_s_setprio(0);

        // per key-chunk kc (keys kc*32..+31): softmax -> Ps band, then PV MFMA.
        // Ps band is wave-private AND time-shared across (kc, qg): in-wave LDS
        // ordering guarantees qg0's read completes before qg1's overwrite.
#pragma unroll
        for (int kc = 0; kc < 2; ++kc) {
            bf16x8 av[4];  // V fragments cached: shared by both q-groups
#pragma unroll
            for (int nt = 0; nt < 4; ++nt)
                av[nt] = *(const bf16x8*)&Vts[cur][(nt * 16 + l16) * 64 + (((kc * 4 + quad) ^ sw) << 3)];
#pragma unroll
            for (int qg = 0; qg < 2; ++qg) {
#pragma unroll
                for (int ntl = 0; ntl < 2; ++ntl) {
                    int nt = kc * 2 + ntl;
                    float p0 = __builtin_amdgcn_exp2f(s[qg][nt][0]);
                    float p1 = __builtin_amdgcn_exp2f(s[qg][nt][1]);
                    unsigned pk0 = __builtin_amdgcn_perm(
                        __builtin_bit_cast(unsigned, p1),
                        __builtin_bit_cast(unsigned, p0), 0x07060302u);
                    float p2 = __builtin_amdgcn_exp2f(s[qg][nt][2]);
                    float p3 = __builtin_amdgcn_exp2f(s[qg][nt][3]);
                    unsigned pk1 = __builtin_amdgcn_perm(
                        __builtin_bit_cast(unsigned, p3),
                        __builtin_bit_cast(unsigned, p2), 0x07060302u);
                    *(uint2*)&Ps[w * 16 + l16][ntl * 16 + quad * 4] = make_uint2(pk0, pk1);
                }
                bf16x8 bp = *(const bf16x8*)&Ps[w * 16 + l16][quad * 8];
                __builtin_amdgcn_s_setprio(1);
                // l_i = P . 1 via ones-MFMA (sums the exact bf16 P used by PV)
                lsum[qg] = __builtin_amdgcn_mfma_f32_16x16x32_bf16(ones, bp, lsum[qg], 0, 0, 0);
                // O^T += V^T(chunk kc) . P^T(chunk kc)
#pragma unroll
                for (int nt = 0; nt < 4; ++nt)
                    acc_o[qg][nt] = __builtin_amdgcn_mfma_f32_16x16x32_bf16(av[nt], bp, acc_o[qg][nt], 0, 0, 0);
                __builtin_amdgcn_s_setprio(0);
            }
        }
        // no trailing barrier: next iteration's __syncthreads covers the
        // read-before-overwrite hazard (prefetch targets the other buffer).
    }

    // epilogue: lsum already holds full row sums (all lanes/regs for q=l16)
#pragma unroll
    for (int qg = 0; qg < 2; ++qg) {
        float rl = 1.0f / lsum[qg][0];
        size_t orow = (qrow0 + w * 32 + qg * 16 + l16) * 1024 + h * 64;
#pragma unroll
        for (int nt = 0; nt < 4; ++nt) {
            ushort4 o4;
            o4.x = f2bf(acc_o[qg][nt][0] * rl);
            o4.y = f2bf(acc_o[qg][nt][1] * rl);
            o4.z = f2bf(acc_o[qg][nt][2] * rl);
            o4.w = f2bf(acc_o[qg][nt][3] * rl);
            *(ushort4*)&O[orow + nt * 16 + quad * 4] = o4;
        }
    }
}

// ---------------- LayerNorm in place on [8192][1024] fp32 ----------------
__global__ __launch_bounds__(256) void ln_kernel(float* __restrict__ io,
    const float* __restrict__ gamma, const float* __restrict__ beta)
{
    int row = blockIdx.x;
    int tid = threadIdx.x;
    float* p = io + (size_t)row * 1024;
    float4 x = *reinterpret_cast<const float4*>(&p[tid << 2]);
    float s = x.x + x.y + x.z + x.w;
    float ss = fmaf(x.x, x.x, fmaf(x.y, x.y, fmaf(x.z, x.z, x.w * x.w)));
#pragma unroll
    for (int off = 32; off > 0; off >>= 1) {
        s  += __shfl_down(s, off);
        ss += __shfl_down(ss, off);
    }
    __shared__ float rs[4], rss[4];
    int lane = tid & 63, wid = tid >> 6;
    if (lane == 0) { rs[wid] = s; rss[wid] = ss; }
    __syncthreads();
    float S = rs[0] + rs[1] + rs[2] + rs[3];
    float SS = rss[0] + rss[1] + rss[2] + rss[3];
    float mu = S * (1.0f / 1024.0f);
    float var = SS * (1.0f / 1024.0f) - mu * mu;
    float rstd = rsqrtf(var + 1e-12f);
    float4 g = *reinterpret_cast<const float4*>(&gamma[tid << 2]);
    float4 be = *reinterpret_cast<const float4*>(&beta[tid << 2]);
    float4 o;
    o.x = (x.x - mu) * rstd * g.x + be.x;
    o.y = (x.y - mu) * rstd * g.y + be.y;
    o.z = (x.z - mu) * rstd * g.z + be.z;
    o.w = (x.w - mu) * rstd * g.w + be.w;
    *reinterpret_cast<float4*>(&p[tid << 2]) = o;
}

// ---------------- launch ----------------
extern "C" void kernel_launch(void* const* d_in, const int* in_sizes, int n_in,
                              void* d_out, int out_size, void* d_ws, size_t ws_size,
                              hipStream_t stream)
{
    (void)in_sizes; (void)n_in; (void)out_size; (void)ws_size;
    const float* hidden = (const float*)d_in[0];
    const float* Wq = (const float*)d_in[1];
    const float* bq = (const float*)d_in[2];
    const float* Wk = (const float*)d_in[3];
    const float* bk = (const float*)d_in[4];
    const float* Wv = (const float*)d_in[5];
    const float* bv = (const float*)d_in[6];
    const float* Wo = (const float*)d_in[7];
    const float* bo = (const float*)d_in[8];
    const float* g  = (const float*)d_in[9];
    const float* be = (const float*)d_in[10];
    float* out = (float*)d_out;

    // workspace layout (Wqt/Wkt/Wvt contiguous => one [2048][1024] B^T matrix)
    u16* hb  = (u16*)d_ws;                       // [8192][1024] bf16 hidden
    u16* Wqt = hb  + (size_t)8192 * 1024;        // [1024][1024] Wq^T
    u16* Wkt = Wqt + (size_t)1024 * 1024;        // [512][1024]  Wk^T
    u16* Wvt = Wkt + (size_t)512 * 1024;         // [512][1024]  Wv^T
    u16* Wot = Wvt + (size_t)512 * 1024;         // [1024][1024] Wo^T
    u16* Qb  = Wot + (size_t)1024 * 1024;        // [8192][1024] Q (then attn out)
    u16* Kb  = Qb  + (size_t)8192 * 1024;        // [8192][512]  K
    u16* Vtb = Kb  + (size_t)8192 * 512;         // [4096][1024] V^T per (b,kvh)
    // total ~66 MB

    cvt_bf16_kernel<<<8192, 256, 0, stream>>>(hidden, hb, 8192 * 1024 / 4);
    cvt_t4_kernel<<<dim3(16, 16, 4), 256, 0, stream>>>(Wq, Wk, Wv, Wo, Wqt, Wkt, Wvt, Wot);

    // fused QKV: N=2048 (Bt = [Wq^T;Wk^T;Wv^T]), writes Qb (unroped), Kb, Vtb (V transposed)
    gemm_qkv<<<dim3(1024), 256, 0, stream>>>(hb, Wqt, bq, bk, bv, Qb, Kb, Vtb);

    // RoPE on K only (Q roped inside attn)
    rope_bf16_kernel<<<8192, 256, 0, stream>>>(Kb, 3, 512, 8192 * 8 * 32);

    attn_mfma<<<dim3(1024), 256, 0, stream>>>(Qb, Kb, Vtb, Qb);

    // out-proj: fp32 out + bias + resid, 2-phase pipelined
    gemm_out<<<dim3(512), 256, 0, stream>>>(Qb, Wot, bo, hidden, out);

    ln_kernel<<<8192, 256, 0, stream>>>(out, g, be);
}

// Round 5
// 234.957 us; speedup vs baseline: 1.1475x; 1.0021x over previous
//
#include <hip/hip_runtime.h>
#include <math.h>
#include <stdint.h>

typedef unsigned short u16;
typedef __bf16 bf16x8 __attribute__((ext_vector_type(8)));
typedef float f32x4 __attribute__((ext_vector_type(4)));

typedef const __attribute__((address_space(1))) void gv_t;
typedef __attribute__((address_space(3))) void lv_t;

__device__ __forceinline__ u16 f2bf(float f) {
    unsigned u = __builtin_bit_cast(unsigned, f);
    return (u16)((u + 0x7FFFu + ((u >> 16) & 1u)) >> 16);
}
__device__ __forceinline__ float bf2f(u16 h) {
    return __builtin_bit_cast(float, (unsigned)h << 16);
}
// async global->LDS, 16B per lane; LDS dest = wave-uniform base + lane*16
__device__ __forceinline__ void gll16(const void* g, void* l) {
    __builtin_amdgcn_global_load_lds((gv_t*)(uintptr_t)g,
                                     (lv_t*)(unsigned)(uintptr_t)l, 16, 0, 0);
}

// ---------------- fused conversions: hidden fp32->bf16 + 4 weight transposes ----
// blocks [0,8192): hidden cvt (float4 per lane). blocks [8192,9216): weight
// fp32 [1024][N] -> bf16 [N][1024] transpose via 64x64 LDS tile.
__global__ __launch_bounds__(256) void cvt_all_kernel(
    const float* __restrict__ hidden, u16* __restrict__ hb,
    const float* __restrict__ w0, const float* __restrict__ w1,
    const float* __restrict__ w2, const float* __restrict__ w3,
    u16* __restrict__ o0, u16* __restrict__ o1,
    u16* __restrict__ o2, u16* __restrict__ o3)
{
    __shared__ u16 t[64][65];
    int bid = blockIdx.x, tid = threadIdx.x;
    if (bid < 8192) {
        int i = bid * 256 + tid;
        float4 f = ((const float4*)hidden)[i];
        ushort4 o = make_ushort4(f2bf(f.x), f2bf(f.y), f2bf(f.z), f2bf(f.w));
        ((ushort4*)hb)[i] = o;
        return;
    }
    int id2 = bid - 8192;                 // 1024 t4 blocks
    int bz = id2 >> 8, by = (id2 >> 4) & 15, bx = id2 & 15;
    const float* in; u16* out; int N;
    switch (bz) {
        case 0: in = w0; out = o0; N = 1024; break;
        case 1: in = w1; out = o1; N = 512;  break;
        case 2: in = w2; out = o2; N = 512;  break;
        default: in = w3; out = o3; N = 1024; break;
    }
    int kb = by * 64, nb = bx * 64;
    if (nb >= N) return;
#pragma unroll
    for (int c = 0; c < 16; ++c) {
        int id = c * 256 + tid;
        int r = id >> 6, n = id & 63;
        t[n][r] = f2bf(in[(size_t)(kb + r) * N + nb + n]);
    }
    __syncthreads();
#pragma unroll
    for (int c = 0; c < 16; ++c) {
        int id = c * 256 + tid;
        int r = id >> 6, n = id & 63;
        out[(size_t)(nb + r) * 1024 + kb + n] = t[r][n];
    }
}

// ---------------- MFMA GEMM body, BK=64, 2-phase dbuf, XOR-swizzled DMA -----
// A: [8192][K] bf16, Bt: [N][K] bf16. 128x128 tile, 256 thr = 4 waves 2x2.
// Unified T3 2-phase pipeline: prologue stages tile 0; per tile: __syncthreads
// (drains tile t's DMA, which flew during tile t-1's compute) -> issue t+1 ->
// ds_read + MFMA. LDS 64 KB -> 2 blocks/CU.
// XCD-chunked remap: hw id%8 = XCD; contiguous nid chunk per XCD so blocks
// sharing A-panels co-locate with the B panel in one 4 MiB L2.
template<int MODE, int NBX>
__device__ __forceinline__ void gemm_body(
    const u16* __restrict__ A, const u16* __restrict__ Bt,
    const float* __restrict__ b0, const float* __restrict__ b1,
    const float* __restrict__ b2,
    const float* __restrict__ resid, float* __restrict__ Cf,
    u16* __restrict__ Qo, u16* __restrict__ Ko, u16* __restrict__ Vto,
    int N, int K)
{
    __shared__ __align__(16) u16 Asl[2][128 * 64];
    __shared__ __align__(16) u16 Bsl[2][128 * 64];
    const int tid = threadIdx.x, lane = tid & 63, w = tid >> 6;
    const int quad = lane >> 4, l16 = lane & 15;
    const int id = blockIdx.x;
    const int chunk = (NBX * 64) >> 3;                // blocks per XCD
    const int nid = (id & 7) * chunk + (id >> 3);     // id%8 -> XCD
    const int bx = nid & (NBX - 1), by = nid / NBX;
    const int bm = by * 128, bn = bx * 128;
    const int wm = (w >> 1) * 64, wn = (w & 1) * 64;

    f32x4 acc[4][4] = {};

    const int dr = lane >> 3;                       // row within 8-row band
    const int dcs = (((lane & 7) ^ dr) << 3);       // swizzled global chunk (elems)
    const u16* Ag = &A[(size_t)(bm + w * 32 + dr) * K + dcs];
    const u16* Bg = &Bt[(size_t)(bn + w * 32 + dr) * K + dcs];

    const int sw = l16 & 7;  // fragment-read swizzle

    const int NT = K >> 6;
#pragma unroll
    for (int c = 0; c < 4; ++c) {  // prologue: stage tile 0 -> buf 0
        gll16(Ag + (size_t)(c * 8) * K, &Asl[0][(w * 32 + c * 8) * 64]);
        gll16(Bg + (size_t)(c * 8) * K, &Bsl[0][(w * 32 + c * 8) * 64]);
    }
    for (int t = 0; t < NT; ++t) {
        const int cur = t & 1;
        // drains this wave's outstanding DMA (tile t, issued during the
        // previous tile's compute) + barrier -> tile t staged everywhere.
        __syncthreads();
        if (t < NT - 1) {
            const int k0 = (t + 1) * 64;
#pragma unroll
            for (int c = 0; c < 4; ++c) {
                gll16(Ag + (size_t)(c * 8) * K + k0, &Asl[cur ^ 1][(w * 32 + c * 8) * 64]);
                gll16(Bg + (size_t)(c * 8) * K + k0, &Bsl[cur ^ 1][(w * 32 + c * 8) * 64]);
            }
        }
        bf16x8 af[4][2], bfr[4][2];
#pragma unroll
        for (int i = 0; i < 4; ++i)
#pragma unroll
            for (int ks = 0; ks < 2; ++ks)
                af[i][ks] = *(const bf16x8*)&Asl[cur][(wm + i * 16 + l16) * 64 + (((ks * 4 + quad) ^ sw) << 3)];
#pragma unroll
        for (int j = 0; j < 4; ++j)
#pragma unroll
            for (int ks = 0; ks < 2; ++ks)
                bfr[j][ks] = *(const bf16x8*)&Bsl[cur][(wn + j * 16 + l16) * 64 + (((ks * 4 + quad) ^ sw) << 3)];
#pragma unroll
        for (int i = 0; i < 4; ++i)
#pragma unroll
            for (int j = 0; j < 4; ++j)
#pragma unroll
                for (int ks = 0; ks < 2; ++ks)
                    acc[i][j] = __builtin_amdgcn_mfma_f32_16x16x32_bf16(af[i][ks], bfr[j][ks], acc[i][j], 0, 0, 0);
        // no trailing barrier: next iteration's __syncthreads covers the
        // read-before-overwrite hazard (prefetch targets the other buffer).
    }

    // epilogue: C/D layout col=lane&15, row=quad*4+reg
#pragma unroll
    for (int j = 0; j < 4; ++j) {
        int col = bn + wn + j * 16 + l16;
        if (MODE == 1) {
            float bb = b0[col];
#pragma unroll
            for (int i = 0; i < 4; ++i) {
                int row0 = bm + wm + i * 16 + quad * 4;
#pragma unroll
                for (int r = 0; r < 4; ++r) {
                    size_t off = (size_t)(row0 + r) * N + col;
                    Cf[off] = acc[i][j][r] + bb + resid[off];
                }
            }
        } else if (col < 1024) {
            float bb = b0[col];
#pragma unroll
            for (int i = 0; i < 4; ++i) {
                int row0 = bm + wm + i * 16 + quad * 4;
#pragma unroll
                for (int r = 0; r < 4; ++r)
                    Qo[(size_t)(row0 + r) * 1024 + col] = f2bf(acc[i][j][r] + bb);
            }
        } else if (col < 1536) {
            int c2 = col - 1024;
            float bb = b1[c2];
#pragma unroll
            for (int i = 0; i < 4; ++i) {
                int row0 = bm + wm + i * 16 + quad * 4;
#pragma unroll
                for (int r = 0; r < 4; ++r)
                    Ko[(size_t)(row0 + r) * 512 + c2] = f2bf(acc[i][j][r] + bb);
            }
        } else {
            int c2 = col - 1536, kvh = c2 >> 6, d = c2 & 63;
            float bb = b2[c2];
#pragma unroll
            for (int i = 0; i < 4; ++i) {
                int row0 = bm + wm + i * 16 + quad * 4;
                int b = row0 >> 10, s = row0 & 1023;
                ushort4 o4;
                o4.x = f2bf(acc[i][j][0] + bb);
                o4.y = f2bf(acc[i][j][1] + bb);
                o4.z = f2bf(acc[i][j][2] + bb);
                o4.w = f2bf(acc[i][j][3] + bb);
                *(ushort4*)&Vto[(size_t)((b * 8 + kvh) * 64 + d) * 1024 + s] = o4;
            }
        }
    }
}

// Distinct kernel names so rocprof rows are unambiguous per mode.
__global__ __launch_bounds__(256) void gemm_qkv(
    const u16* __restrict__ A, const u16* __restrict__ Bt,
    const float* __restrict__ b0, const float* __restrict__ b1,
    const float* __restrict__ b2,
    u16* __restrict__ Qo, u16* __restrict__ Ko, u16* __restrict__ Vto)
{
    gemm_body<0, 16>(A, Bt, b0, b1, b2, nullptr, nullptr, Qo, Ko, Vto, 2048, 1024);
}

__global__ __launch_bounds__(256) void gemm_out(
    const u16* __restrict__ A, const u16* __restrict__ Bt,
    const float* __restrict__ b0,
    const float* __restrict__ resid, float* __restrict__ Cf)
{
    gemm_body<1, 8>(A, Bt, b0, nullptr, nullptr, resid, Cf,
                    nullptr, nullptr, nullptr, 1024, 1024);
}

// ---------------- RoPE (interleaved), in place on bf16 K, 4 pairs/thread ----
// K layout [8192][512] (kvh*64+d). thread: 4 consecutive pairs = uint4.
__global__ __launch_bounds__(256) void rope_bf16_kernel(u16* __restrict__ x)
{
    int idx = blockIdx.x * 256 + threadIdx.x;   // 524288 total
    int jg = idx & 7;                           // group of 4 pairs
    int h = (idx >> 3) & 7;                     // kvh
    int row = idx >> 6;
    float fpos = (float)(row & 1023);
    uint4 u4 = *(uint4*)&x[(size_t)row * 512 + h * 64 + jg * 8];
    unsigned* uw = &u4.x;
#pragma unroll
    for (int t = 0; t < 4; ++t) {
        int j = jg * 4 + t;
        float inv = exp2f((float)j * -0.4152410118609203f);  // 10000^(-2j/64)
        float sn, cs;
        sincosf(fpos * inv, &sn, &cs);
        unsigned u = uw[t];
        float x1 = bf2f((u16)(u & 0xffff)), x2 = bf2f((u16)(u >> 16));
        float y1 = x1 * cs - x2 * sn, y2 = x1 * sn + x2 * cs;
        uw[t] = (unsigned)f2bf(y1) | ((unsigned)f2bf(y2) << 16);
    }
    *(uint4*)&x[(size_t)row * 512 + h * 64 + jg * 8] = u4;
}

// ---------------- MFMA flash attention: 128 q/block, fused Q-RoPE -----------
// Q: [8192][1024] bf16 (h*64+d, UNroped). K: [8192][512] (kvh*64+d, roped).
// Vt: [(b*8+kvh)*64+d][1024 keys] bf16 (pre-transposed).
// T3 2-phase: double-buffered Ks/Vts, one __syncthreads per tile (its vmcnt(0)
// drain is exactly tile kt's DMA, in flight during kt-1's compute).
// REGISTER softmax->PV (no Ps LDS): MFMA key<->(quad,elem) mapping only needs
// P and V to AGREE, so PV uses the key order QK^T's C-layout already gives:
// lane(q=l16, quad) holds keys {kc*32+4q+r, kc*32+16+4q+r}. P packs in-reg
// (exp2 -> perm); V fragment = two ds_read_b64 halves (chunks kc*4+(q>>1),
// +2, XOR-swizzle preserved, bank-uniform). Deletes 8 ds_write + 4 ds_read +
// 4 lgkmcnt serialization points per tile. LDS 32 KB -> 4 blocks/CU,
// grid 1024 = 256 CU x 4 fully co-resident.
// XCD-chunked swizzle: each batch b (K+V 2.1 MB) pinned to one XCD L2
// (verified R4: FETCH 74 -> 16.5 MB).
__global__ __launch_bounds__(256, 4) void attn_mfma(
    const u16* __restrict__ Q, const u16* __restrict__ K,
    const u16* __restrict__ Vt, u16* __restrict__ O)
{
    __shared__ __align__(16) u16 Ks[2][64 * 64];   // [buf][key][d], swizzled chunks
    __shared__ __align__(16) u16 Vts[2][64 * 64];  // [buf][d][key], swizzled chunks

    const int tid = threadIdx.x, lane = tid & 63, w = tid >> 6;
    const int quad = lane >> 4, l16 = lane & 15;
    const int id = blockIdx.x;
    const int nid = (id & 7) * 128 + (id >> 3);    // XCD-chunked (id%8 -> XCD)
    const int qt = nid & 7, h = (nid >> 3) & 15, b = nid >> 7;
    const int kvh = h >> 1;
    const size_t qrow0 = (size_t)b * 1024 + qt * 128;
    const size_t krow0 = (size_t)b * 1024;
    const u16* Vg = Vt + (size_t)((b * 8 + kvh) * 64) * 1024;

    // DMA staging: per wave 16 rows each of K,V^T; 2 calls of 8 rows each.
    const int dr = lane >> 3;                    // row in 8-row band
    const int dcs = (((lane & 7) ^ dr) << 3);    // swizzled global chunk (elems)
    const u16* Kg0 = &K[(krow0 + w * 16 + dr) * 512 + kvh * 64 + dcs];
    const u16* Vg0 = &Vg[(size_t)(w * 16 + dr) * 1024 + dcs];
    const int sw = l16 & 7;
    const float C1 = 0.18033688011112043f;  // 0.125 * log2(e), folded into Q

    // prologue: stage tile 0 into buffer 0 (overlaps Q-RoPE prep below)
#pragma unroll
    for (int c = 0; c < 2; ++c) {
        gll16(Kg0 + (size_t)(c * 8) * 512, &Ks[0][(w * 16 + c * 8) * 64]);
        gll16(Vg0 + (size_t)(c * 8) * 1024, &Vts[0][(w * 16 + c * 8) * 64]);
    }

    // Q fragments with RoPE (and softmax scale C1) applied in-register.
    bf16x8 qf[2][2];
#pragma unroll
    for (int qg = 0; qg < 2; ++qg) {
        int qrow = w * 32 + qg * 16 + l16;
        float fpos = (float)(qt * 128 + qrow);
#pragma unroll
        for (int ks = 0; ks < 2; ++ks) {
            uint4 qraw = *(const uint4*)&Q[(qrow0 + qrow) * 1024 + h * 64 + ks * 32 + quad * 8];
            unsigned o_[4];
#pragma unroll
            for (int t = 0; t < 4; ++t) {
                int j = ks * 16 + quad * 4 + t;
                float inv = exp2f((float)j * -0.4152410118609203f);
                float sn_, cs_;
                sincosf(fpos * inv, &sn_, &cs_);
                cs_ *= C1; sn_ *= C1;            // fold softmax scale into Q
                unsigned u = (&qraw.x)[t];
                float x1 = bf2f((u16)(u & 0xffff)), x2 = bf2f((u16)(u >> 16));
                float y1 = x1 * cs_ - x2 * sn_, y2 = x1 * sn_ + x2 * cs_;
                o_[t] = (unsigned)f2bf(y1) | ((unsigned)f2bf(y2) << 16);
            }
            qf[qg][ks] = __builtin_bit_cast(bf16x8, make_uint4(o_[0], o_[1], o_[2], o_[3]));
        }
    }

    f32x4 acc_o[2][4] = {};
    f32x4 lsum[2] = {};  // ones-MFMA row-sum accumulator
    const bf16x8 ones = __builtin_bit_cast(bf16x8,
        make_uint4(0x3F803F80u, 0x3F803F80u, 0x3F803F80u, 0x3F803F80u));

    for (int kt = 0; kt < 16; ++kt) {
        const int cur = kt & 1;
        // drains this wave's outstanding DMA (tile kt, in flight during the
        // previous tile's compute) + barrier -> tile kt staged everywhere.
        __syncthreads();

        // prefetch tile kt+1 into the other buffer.
        if (kt < 15) {
#pragma unroll
            for (int c = 0; c < 2; ++c) {
                gll16(Kg0 + (size_t)((kt + 1) * 64 + c * 8) * 512,
                      &Ks[cur ^ 1][(w * 16 + c * 8) * 64]);
                gll16(Vg0 + (size_t)(c * 8) * 1024 + (kt + 1) * 64,
                      &Vts[cur ^ 1][(w * 16 + c * 8) * 64]);
            }
        }

        // S^T = K . Q^T : s[qg][nt] holds keys nt*16+quad*4+(0..3) for q=l16
        f32x4 s[2][4] = {};
        __builtin_amdgcn_s_setprio(1);
#pragma unroll
        for (int ks = 0; ks < 2; ++ks) {
#pragma unroll
            for (int nt = 0; nt < 4; ++nt) {
                bf16x8 ak = *(const bf16x8*)&Ks[cur][(nt * 16 + l16) * 64 + (((ks * 4 + quad) ^ sw) << 3)];
                s[0][nt] = __builtin_amdgcn_mfma_f32_16x16x32_bf16(ak, qf[0][ks], s[0][nt], 0, 0, 0);
                s[1][nt] = __builtin_amdgcn_mfma_f32_16x16x32_bf16(ak, qf[1][ks], s[1][nt], 0, 0, 0);
            }
        }
        __builtin_amdgcn_s_setprio(0);

        // per key-chunk kc: register softmax -> PV. Key order per (quad,elem):
        // e<4 -> kc*32+4*quad+e (from nt=kc*2), e>=4 -> kc*32+16+4*quad+(e-4)
        // (from nt=kc*2+1). V fragments read with the SAME order: two b64
        // halves of logical chunks kc*4+(quad>>1) and kc*4+2+(quad>>1),
        // half-select (quad&1), physical = logical ^ sw.
#pragma unroll
        for (int kc = 0; kc < 2; ++kc) {
            uint2 vlo[4], vhi[4];
            const int pcl = ((kc * 4 + (quad >> 1)) ^ sw) * 8 + (quad & 1) * 4;
            const int pch = ((kc * 4 + 2 + (quad >> 1)) ^ sw) * 8 + (quad & 1) * 4;
#pragma unroll
            for (int nt = 0; nt < 4; ++nt) {
                vlo[nt] = *(const uint2*)&Vts[cur][(nt * 16 + l16) * 64 + pcl];
                vhi[nt] = *(const uint2*)&Vts[cur][(nt * 16 + l16) * 64 + pch];
            }
#pragma unroll
            for (int qg = 0; qg < 2; ++qg) {
                unsigned pk[4];
#pragma unroll
                for (int ntl = 0; ntl < 2; ++ntl) {
                    int nt = kc * 2 + ntl;
                    float p0 = __builtin_amdgcn_exp2f(s[qg][nt][0]);
                    float p1 = __builtin_amdgcn_exp2f(s[qg][nt][1]);
                    pk[ntl * 2 + 0] = __builtin_amdgcn_perm(
                        __builtin_bit_cast(unsigned, p1),
                        __builtin_bit_cast(unsigned, p0), 0x07060302u);
                    float p2 = __builtin_amdgcn_exp2f(s[qg][nt][2]);
                    float p3 = __builtin_amdgcn_exp2f(s[qg][nt][3]);
                    pk[ntl * 2 + 1] = __builtin_amdgcn_perm(
                        __builtin_bit_cast(unsigned, p3),
                        __builtin_bit_cast(unsigned, p2), 0x07060302u);
                }
                bf16x8 bp = __builtin_bit_cast(bf16x8,
                    make_uint4(pk[0], pk[1], pk[2], pk[3]));
                __builtin_amdgcn_s_setprio(1);
                // l_i = P . 1 via ones-MFMA (key order irrelevant for the sum)
                lsum[qg] = __builtin_amdgcn_mfma_f32_16x16x32_bf16(ones, bp, lsum[qg], 0, 0, 0);
#pragma unroll
                for (int nt = 0; nt < 4; ++nt) {
                    bf16x8 av = __builtin_bit_cast(bf16x8,
                        make_uint4(vlo[nt].x, vlo[nt].y, vhi[nt].x, vhi[nt].y));
                    acc_o[qg][nt] = __builtin_amdgcn_mfma_f32_16x16x32_bf16(av, bp, acc_o[qg][nt], 0, 0, 0);
                }
                __builtin_amdgcn_s_setprio(0);
            }
        }
        // no trailing barrier: next iteration's __syncthreads covers the
        // read-before-overwrite hazard (prefetch targets the other buffer).
    }

    // epilogue: lsum already holds full row sums (all lanes/regs for q=l16)
#pragma unroll
    for (int qg = 0; qg < 2; ++qg) {
        float rl = 1.0f / lsum[qg][0];
        size_t orow = (qrow0 + w * 32 + qg * 16 + l16) * 1024 + h * 64;
#pragma unroll
        for (int nt = 0; nt < 4; ++nt) {
            ushort4 o4;
            o4.x = f2bf(acc_o[qg][nt][0] * rl);
            o4.y = f2bf(acc_o[qg][nt][1] * rl);
            o4.z = f2bf(acc_o[qg][nt][2] * rl);
            o4.w = f2bf(acc_o[qg][nt][3] * rl);
            *(ushort4*)&O[orow + nt * 16 + quad * 4] = o4;
        }
    }
}

// ---------------- LayerNorm in place on [8192][1024] fp32 ----------------
__global__ __launch_bounds__(256) void ln_kernel(float* __restrict__ io,
    const float* __restrict__ gamma, const float* __restrict__ beta)
{
    int row = blockIdx.x;
    int tid = threadIdx.x;
    float* p = io + (size_t)row * 1024;
    float4 x = *reinterpret_cast<const float4*>(&p[tid << 2]);
    float s = x.x + x.y + x.z + x.w;
    float ss = fmaf(x.x, x.x, fmaf(x.y, x.y, fmaf(x.z, x.z, x.w * x.w)));
#pragma unroll
    for (int off = 32; off > 0; off >>= 1) {
        s  += __shfl_down(s, off);
        ss += __shfl_down(ss, off);
    }
    __shared__ float rs[4], rss[4];
    int lane = tid & 63, wid = tid >> 6;
    if (lane == 0) { rs[wid] = s; rss[wid] = ss; }
    __syncthreads();
    float S = rs[0] + rs[1] + rs[2] + rs[3];
    float SS = rss[0] + rss[1] + rss[2] + rss[3];
    float mu = S * (1.0f / 1024.0f);
    float var = SS * (1.0f / 1024.0f) - mu * mu;
    float rstd = rsqrtf(var + 1e-12f);
    float4 g = *reinterpret_cast<const float4*>(&gamma[tid << 2]);
    float4 be = *reinterpret_cast<const float4*>(&beta[tid << 2]);
    float4 o;
    o.x = (x.x - mu) * rstd * g.x + be.x;
    o.y = (x.y - mu) * rstd * g.y + be.y;
    o.z = (x.z - mu) * rstd * g.z + be.z;
    o.w = (x.w - mu) * rstd * g.w + be.w;
    *reinterpret_cast<float4*>(&p[tid << 2]) = o;
}

// ---------------- launch ----------------
extern "C" void kernel_launch(void* const* d_in, const int* in_sizes, int n_in,
                              void* d_out, int out_size, void* d_ws, size_t ws_size,
                              hipStream_t stream)
{
    (void)in_sizes; (void)n_in; (void)out_size; (void)ws_size;
    const float* hidden = (const float*)d_in[0];
    const float* Wq = (const float*)d_in[1];
    const float* bq = (const float*)d_in[2];
    const float* Wk = (const float*)d_in[3];
    const float* bk = (const float*)d_in[4];
    const float* Wv = (const float*)d_in[5];
    const float* bv = (const float*)d_in[6];
    const float* Wo = (const float*)d_in[7];
    const float* bo = (const float*)d_in[8];
    const float* g  = (const float*)d_in[9];
    const float* be = (const float*)d_in[10];
    float* out = (float*)d_out;

    // workspace layout (Wqt/Wkt/Wvt contiguous => one [2048][1024] B^T matrix)
    u16* hb  = (u16*)d_ws;                       // [8192][1024] bf16 hidden
    u16* Wqt = hb  + (size_t)8192 * 1024;        // [1024][1024] Wq^T
    u16* Wkt = Wqt + (size_t)1024 * 1024;        // [512][1024]  Wk^T
    u16* Wvt = Wkt + (size_t)512 * 1024;         // [512][1024]  Wv^T
    u16* Wot = Wvt + (size_t)512 * 1024;         // [1024][1024] Wo^T
    u16* Qb  = Wot + (size_t)1024 * 1024;        // [8192][1024] Q (then attn out)
    u16* Kb  = Qb  + (size_t)8192 * 1024;        // [8192][512]  K
    u16* Vtb = Kb  + (size_t)8192 * 512;         // [4096][1024] V^T per (b,kvh)
    // total ~66 MB

    cvt_all_kernel<<<9216, 256, 0, stream>>>(hidden, hb, Wq, Wk, Wv, Wo,
                                             Wqt, Wkt, Wvt, Wot);

    // fused QKV: N=2048 (Bt = [Wq^T;Wk^T;Wv^T]), writes Qb (unroped), Kb, Vtb
    gemm_qkv<<<dim3(1024), 256, 0, stream>>>(hb, Wqt, bq, bk, bv, Qb, Kb, Vtb);

    // RoPE on K only (Q roped inside attn)
    rope_bf16_kernel<<<2048, 256, 0, stream>>>(Kb);

    attn_mfma<<<dim3(1024), 256, 0, stream>>>(Qb, Kb, Vtb, Qb);

    // out-proj: fp32 out + bias + resid, 2-phase pipelined
    gemm_out<<<dim3(512), 256, 0, stream>>>(Qb, Wot, bo, hidden, out);

    ln_kernel<<<8192, 256, 0, stream>>>(out, g, be);
}